// Round 4
// baseline (3429.613 us; speedup 1.0000x reference)
//
#include <hip/hip_runtime.h>
#include <math.h>

#define DEVI __device__ __forceinline__

DEVI float silu_f(float x){ return x / (1.0f + __expf(-x)); }

// ---------------- utility: zero a float region ----------------
__global__ void k_zero(float* p, int n){
  int i = blockIdx.x*256 + threadIdx.x;
  if (i < n) p[i] = 0.f;
}

// ---------------- weight transforms ----------------
struct XJob { const float* src; float* dst; int ci, co, n, deconv; };
struct XArgs { XJob j[10]; };

__global__ void k_xform(XArgs a){
  XJob jb = a.j[blockIdx.y];
  int e = blockIdx.x*256 + threadIdx.x;
  if (e >= jb.n) return;
  if (!jb.deconv){
    int co = e % jb.co; int k = e / jb.co; int ci = k/9; int jj = k - ci*9;
    jb.dst[e] = jb.src[(co*jb.ci + ci)*9 + jj];
  } else {
    int co = e % 3; int r = e/3; int ci = r & 127; int tap = r >> 7;
    int ky = tap >> 2, kx = tap & 3;
    jb.dst[e] = jb.src[((ci*3 + co)*4 + ky)*4 + kx];
  }
}

// ---------------- conv 3x3, CIN=3, NCHW input -> NHWC output, silu ----------------
template<int CO>
__global__ __launch_bounds__(256)
void k_conv_cin3(const float* __restrict__ x, const float* __restrict__ wt,
                 const float* __restrict__ bias, float* __restrict__ out){
  constexpr int CO4 = CO/4;
  constexpr int PPB = 256/CO4;
  int t = threadIdx.x;
  int co4 = t % CO4, pi = t / CO4;
  int p = blockIdx.x*PPB + pi;
  int b = p >> 16;
  int rem = p & 65535;
  int y = rem >> 8, xx = rem & 255;
  float4 acc = *(const float4*)(bias + co4*4);
  #pragma unroll
  for (int ci = 0; ci < 3; ++ci)
    for (int dy = 0; dy < 3; ++dy){
      int yy = y + dy - 1;
      if ((unsigned)yy >= 256u) continue;
      for (int dx = 0; dx < 3; ++dx){
        int xg = xx + dx - 1;
        if ((unsigned)xg >= 256u) continue;
        float v = x[(((size_t)b*3 + ci)*256 + yy)*256 + xg];
        int k = ci*9 + dy*3 + dx;
        float4 w = *(const float4*)(wt + (size_t)k*CO + co4*4);
        acc.x += v*w.x; acc.y += v*w.y; acc.z += v*w.z; acc.w += v*w.w;
      }
    }
  float4 o; o.x = silu_f(acc.x); o.y = silu_f(acc.y); o.z = silu_f(acc.z); o.w = silu_f(acc.w);
  *(float4*)(out + (size_t)p*CO + co4*4) = o;
}

// ---------------- CIN=128 3x3 conv, NHWC, silu, optional bn scale on input ----------------
template<int STRIDE, int PXB, int CO, int COPT>
__global__ __launch_bounds__(256, 4)
void k_conv128(const float* __restrict__ in, const float* __restrict__ wt,
               const float* __restrict__ bias, float* __restrict__ out,
               const float* __restrict__ sc, const float* __restrict__ sh,
               int H_in, int W_in){
  constexpr int WT = PXB*STRIDE + 2;
  constexpr int COG = CO/COPT;
  constexpr int PG = 256/COG;
  constexpr int PPT = PXB/PG;
  constexpr int NV = COPT/4;
  constexpr int LSTR = 132;
  constexpr int SEGS = 128/PXB;
  __shared__ float lds[WT*LSTR];
  __shared__ float scl[128], shl[128];
  int t = threadIdx.x;
  int cog = t % COG, pg = t / COG;
  int blk = blockIdx.x;
  int seg = blk % SEGS; int oy = (blk/SEGS) & 127; int b = blk/(SEGS*128);
  int x0 = seg*PXB;
  bool hasS = (sc != nullptr);
  if (t < 128){ scl[t] = hasS ? sc[t] : 1.f; shl[t] = hasS ? sh[t] : 0.f; }
  __syncthreads();
  float acc[PPT][COPT];
  #pragma unroll
  for (int i=0;i<PPT;i++)
    #pragma unroll
    for (int v=0;v<NV;v++){
      float4 bv = *(const float4*)(bias + cog*COPT + v*4);
      acc[i][v*4+0]=bv.x; acc[i][v*4+1]=bv.y; acc[i][v*4+2]=bv.z; acc[i][v*4+3]=bv.w;
    }
  const int gx0 = x0*STRIDE - 1;
  for (int dy=0; dy<3; ++dy){
    int iy = oy*STRIDE + dy - 1;
    if ((unsigned)iy < (unsigned)H_in){
      const float* rowp = in + ((size_t)b*H_in + iy)*(size_t)W_in*128;
      for (int i = t; i < WT*32; i += 256){
        int col = i >> 5; int cq = i & 31;
        int gx = gx0 + col;
        float4 v = make_float4(0.f,0.f,0.f,0.f);
        if ((unsigned)gx < (unsigned)W_in){
          v = *(const float4*)(rowp + (size_t)gx*128 + cq*4);
          v.x = v.x*scl[cq*4+0] + shl[cq*4+0];
          v.y = v.y*scl[cq*4+1] + shl[cq*4+1];
          v.z = v.z*scl[cq*4+2] + shl[cq*4+2];
          v.w = v.w*scl[cq*4+3] + shl[cq*4+3];
        }
        *(float4*)(&lds[col*LSTR + cq*4]) = v;
      }
      __syncthreads();
      #pragma unroll
      for (int dx=0; dx<3; ++dx){
        const float* wdd = wt + (size_t)(dy*3+dx)*CO + cog*COPT;
        for (int cq=0; cq<32; ++cq){
          float4 a4[PPT];
          #pragma unroll
          for (int i=0;i<PPT;i++)
            a4[i] = *(const float4*)(&lds[((pg*PPT+i)*STRIDE+dx)*LSTR + cq*4]);
          #pragma unroll
          for (int cc=0; cc<4; ++cc){
            const float* wk = wdd + (cq*4+cc)*9*CO;
            float4 w0 = *(const float4*)(wk);
            float4 w1;
            if (NV==2) w1 = *(const float4*)(wk + 4);
            #pragma unroll
            for (int i=0;i<PPT;i++){
              float av = (cc==0) ? a4[i].x : (cc==1) ? a4[i].y : (cc==2) ? a4[i].z : a4[i].w;
              acc[i][0] += av*w0.x; acc[i][1] += av*w0.y; acc[i][2] += av*w0.z; acc[i][3] += av*w0.w;
              if (NV==2){
                acc[i][4] += av*w1.x; acc[i][5] += av*w1.y; acc[i][6] += av*w1.z; acc[i][7] += av*w1.w;
              }
            }
          }
        }
      }
      __syncthreads();
    }
  }
  #pragma unroll
  for (int i=0;i<PPT;i++){
    int px = x0 + pg*PPT + i;
    float* op = out + (((size_t)b*128 + oy)*128 + px)*CO + cog*COPT;
    #pragma unroll
    for (int v=0;v<NV;v++){
      float4 o;
      o.x = silu_f(acc[i][v*4+0]); o.y = silu_f(acc[i][v*4+1]);
      o.z = silu_f(acc[i][v*4+2]); o.w = silu_f(acc[i][v*4+3]);
      *(float4*)(op + v*4) = o;
    }
  }
}

// ---------------- CIN=16 3x3 stride2 conv (e0n stem), LDS stride 20 ----------------
template<int CIN, int CO, int STRIDE, int PXB>
__global__ __launch_bounds__(256)
void k_rowconv(const float* __restrict__ in, const float* __restrict__ wt,
               const float* __restrict__ bias, float* __restrict__ out,
               int H_in, int W_in){
  constexpr int WT = PXB*STRIDE + 2;
  constexpr int CO8 = CO/8;
  constexpr int PG = 256/CO8;
  constexpr int PPT = PXB/PG;
  constexpr int SEGS = 128/PXB;
  constexpr int LSTR = CIN + 4;
  __shared__ float lds[WT*LSTR];
  int t = threadIdx.x;
  int co8 = t % CO8, pg = t / CO8;
  int blk = blockIdx.x;
  int seg = blk % SEGS; int oy = (blk/SEGS) & 127; int b = blk/(SEGS*128);
  int x0 = seg*PXB;
  float acc[PPT][8];
  {
    float4 b0 = *(const float4*)(bias + co8*8);
    float4 b1 = *(const float4*)(bias + co8*8 + 4);
    #pragma unroll
    for (int i=0;i<PPT;i++){
      acc[i][0]=b0.x; acc[i][1]=b0.y; acc[i][2]=b0.z; acc[i][3]=b0.w;
      acc[i][4]=b1.x; acc[i][5]=b1.y; acc[i][6]=b1.z; acc[i][7]=b1.w;
    }
  }
  const int gx0 = x0*STRIDE - 1;
  for (int dy=0; dy<3; ++dy){
    int iy = oy*STRIDE + dy - 1;
    if ((unsigned)iy < (unsigned)H_in){
      const float* rowp = in + ((size_t)b*H_in + iy)*(size_t)W_in*CIN;
      for (int i = t; i < WT*(CIN/4); i += 256){
        int col = i / (CIN/4); int cq = i % (CIN/4);
        int gx = gx0 + col;
        float4 v = make_float4(0.f,0.f,0.f,0.f);
        if ((unsigned)gx < (unsigned)W_in)
          v = *(const float4*)(rowp + (size_t)gx*CIN + cq*4);
        *(float4*)(&lds[col*LSTR + cq*4]) = v;
      }
      __syncthreads();
      for (int dx=0; dx<3; ++dx){
        for (int cq=0; cq<CIN/4; ++cq){
          float4 a4[PPT];
          #pragma unroll
          for (int i=0;i<PPT;i++){
            int lx = (pg*PPT + i)*STRIDE + dx;
            a4[i] = *(const float4*)(&lds[lx*LSTR + cq*4]);
          }
          const float* wk = wt + ((size_t)(cq*4)*9 + dy*3 + dx)*CO + co8*8;
          #pragma unroll
          for (int cc=0; cc<4; ++cc){
            float4 w0 = *(const float4*)(wk + (size_t)cc*9*CO);
            float4 w1 = *(const float4*)(wk + (size_t)cc*9*CO + 4);
            #pragma unroll
            for (int i=0;i<PPT;i++){
              float av = (cc==0) ? a4[i].x : (cc==1) ? a4[i].y : (cc==2) ? a4[i].z : a4[i].w;
              acc[i][0] += av*w0.x; acc[i][1] += av*w0.y; acc[i][2] += av*w0.z; acc[i][3] += av*w0.w;
              acc[i][4] += av*w1.x; acc[i][5] += av*w1.y; acc[i][6] += av*w1.z; acc[i][7] += av*w1.w;
            }
          }
        }
      }
      __syncthreads();
    }
  }
  #pragma unroll
  for (int i=0;i<PPT;i++){
    int px = x0 + pg*PPT + i;
    float4 o0, o1;
    o0.x = silu_f(acc[i][0]); o0.y = silu_f(acc[i][1]); o0.z = silu_f(acc[i][2]); o0.w = silu_f(acc[i][3]);
    o1.x = silu_f(acc[i][4]); o1.y = silu_f(acc[i][5]); o1.z = silu_f(acc[i][6]); o1.w = silu_f(acc[i][7]);
    float* op = out + (((size_t)b*128 + oy)*128 + px)*CO + co8*8;
    *(float4*)op = o0; *(float4*)(op+4) = o1;
  }
}

// ---------------- memcell weights ----------------
__global__ __launch_bounds__(256)
void k_weights(const float* __restrict__ z, const float* __restrict__ zhat,
               float* __restrict__ wT, const float* __restrict__ sc,
               const float* __restrict__ sh, int T){
  __shared__ float zl[128*16];
  __shared__ float zn[128];
  __shared__ float scl[16], shl[16];
  int t = threadIdx.x;
  if (t < 128){
    float s2 = 0.f;
    #pragma unroll
    for (int j=0;j<16;j++){ float v = zhat[t*16+j]; zl[t*16+j] = v; s2 += v*v; }
    zn[t] = s2;
  }
  if (t < 16){ scl[t] = sc ? sc[t] : 1.f; shl[t] = sh ? sh[t] : 0.f; }
  __syncthreads();
  size_t tok = (size_t)blockIdx.x*256 + t;
  float zr[16];
  #pragma unroll
  for (int q=0;q<4;q++){
    float4 v = *(const float4*)(z + tok*16 + q*4);
    zr[q*4+0] = v.x*scl[q*4+0]+shl[q*4+0];
    zr[q*4+1] = v.y*scl[q*4+1]+shl[q*4+1];
    zr[q*4+2] = v.z*scl[q*4+2]+shl[q*4+2];
    zr[q*4+3] = v.w*scl[q*4+3]+shl[q*4+3];
  }
  float mx = -1e30f;
  for (int m=0;m<128;m++){
    float d=0.f;
    #pragma unroll
    for (int j=0;j<16;j++) d += zr[j]*zl[m*16+j];
    float s = 5.0f*(2.f*d - zn[m]);
    mx = fmaxf(mx, s);
  }
  float sum=0.f;
  for (int m=0;m<128;m++){
    float d=0.f;
    #pragma unroll
    for (int j=0;j<16;j++) d += zr[j]*zl[m*16+j];
    sum += __expf(5.0f*(2.f*d - zn[m]) - mx);
  }
  float inv = 1.f/sum;
  for (int m=0;m<128;m++){
    float d=0.f;
    #pragma unroll
    for (int j=0;j<16;j++) d += zr[j]*zl[m*16+j];
    wT[(size_t)m*T + tok] = __expf(5.0f*(2.f*d - zn[m]) - mx)*inv;
  }
}

// ---------------- S=128 GEMM: out[t][:] = (ADD?addsrc:0) + w[t,:] @ (mat1+mat2) ----------------
template<bool ADD, bool DOTANH, bool STATS, bool MAT2>
__global__ __launch_bounds__(256)
void k_gemm128(const float* __restrict__ wT, const float* __restrict__ mat1,
               const float* __restrict__ mat2, const float* __restrict__ addsrc,
               float* __restrict__ dst, double* __restrict__ stats, int T){
  __shared__ float4 ml4[128*32];
  __shared__ float ssum[128], ssq[128];
  int t = threadIdx.x;
  if (STATS && t < 128){ ssum[t]=0.f; ssq[t]=0.f; }
  for (int i=t; i < 128*32; i += 256){
    float4 v = ((const float4*)mat1)[i];
    if (MAT2){ float4 u = ((const float4*)mat2)[i]; v.x+=u.x; v.y+=u.y; v.z+=u.z; v.w+=u.w; }
    ml4[i] = v;
  }
  __syncthreads();
  int s16 = t & 15, tg = t >> 4;
  size_t tb = (size_t)blockIdx.x*64;
  float accA[4][4], accB[4][4];
  #pragma unroll
  for (int i=0;i<4;i++) for (int j=0;j<4;j++){ accA[i][j]=0.f; accB[i][j]=0.f; }
  const float* wp = wT + tb + tg*4;
  #pragma unroll 4
  for (int m=0;m<128;m++){
    float4 wv = *(const float4*)(wp + (size_t)m*T);
    float4 c0 = ml4[m*32 + s16];
    float4 c1 = ml4[m*32 + 16 + s16];
    float w[4] = {wv.x,wv.y,wv.z,wv.w};
    #pragma unroll
    for (int i=0;i<4;i++){
      accA[i][0] += w[i]*c0.x; accA[i][1] += w[i]*c0.y; accA[i][2] += w[i]*c0.z; accA[i][3] += w[i]*c0.w;
      accB[i][0] += w[i]*c1.x; accB[i][1] += w[i]*c1.y; accB[i][2] += w[i]*c1.z; accB[i][3] += w[i]*c1.w;
    }
  }
  int colA = s16*4, colB = 64 + s16*4;
  float lsA[4], lqA[4], lsB[4], lqB[4];
  #pragma unroll
  for (int j=0;j<4;j++){ lsA[j]=0.f; lqA[j]=0.f; lsB[j]=0.f; lqB[j]=0.f; }
  #pragma unroll
  for (int i=0;i<4;i++){
    size_t tok = tb + tg*4 + i;
    float oA[4], oB[4];
    #pragma unroll
    for (int j=0;j<4;j++){ oA[j]=accA[i][j]; oB[j]=accB[i][j]; }
    if (ADD){
      float4 a0 = *(const float4*)(addsrc + tok*128 + colA);
      float4 a1 = *(const float4*)(addsrc + tok*128 + colB);
      oA[0]+=a0.x; oA[1]+=a0.y; oA[2]+=a0.z; oA[3]+=a0.w;
      oB[0]+=a1.x; oB[1]+=a1.y; oB[2]+=a1.z; oB[3]+=a1.w;
    }
    if (DOTANH){
      #pragma unroll
      for (int j=0;j<4;j++){ oA[j]=tanhf(oA[j]); oB[j]=tanhf(oB[j]); }
    }
    float4 r0 = {oA[0],oA[1],oA[2],oA[3]}, r1 = {oB[0],oB[1],oB[2],oB[3]};
    *(float4*)(dst + tok*128 + colA) = r0;
    *(float4*)(dst + tok*128 + colB) = r1;
    if (STATS){
      #pragma unroll
      for (int j=0;j<4;j++){
        lsA[j]+=oA[j]; lqA[j]+=oA[j]*oA[j];
        lsB[j]+=oB[j]; lqB[j]+=oB[j]*oB[j];
      }
    }
  }
  if (STATS){
    #pragma unroll
    for (int j=0;j<4;j++){
      atomicAdd(&ssum[colA+j], lsA[j]); atomicAdd(&ssq[colA+j], lqA[j]);
      atomicAdd(&ssum[colB+j], lsB[j]); atomicAdd(&ssq[colB+j], lqB[j]);
    }
    __syncthreads();
    if (t < 128){
      atomicAdd(&stats[t], (double)ssum[t]);
      atomicAdd(&stats[128+t], (double)ssq[t]);
    }
  }
}

// ---------------- S=16 GEMM ----------------
template<bool ADD, bool DOTANH, bool STATS>
__global__ __launch_bounds__(256)
void k_gemm16(const float* __restrict__ wT, const float* __restrict__ mat1,
              const float* __restrict__ addsrc, float* __restrict__ dst,
              double* __restrict__ stats, int T){
  __shared__ float ml[128*16];
  __shared__ float ssum[16], ssq[16];
  int t = threadIdx.x;
  if (STATS && t < 16){ ssum[t]=0.f; ssq[t]=0.f; }
  for (int i=t; i < 128*4; i += 256)
    ((float4*)ml)[i] = ((const float4*)mat1)[i];
  __syncthreads();
  size_t tb = (size_t)blockIdx.x*128;
  int s8 = t & 1, tg = t >> 1;
  float acc[8];
  #pragma unroll
  for (int j=0;j<8;j++) acc[j]=0.f;
  size_t tok = tb + tg;
  const float* wp = wT + tok;
  #pragma unroll 4
  for (int m=0;m<128;m++){
    float wv = wp[(size_t)m*T];
    float4 c0 = *(const float4*)(&ml[m*16 + s8*8]);
    float4 c1 = *(const float4*)(&ml[m*16 + s8*8 + 4]);
    acc[0]+=wv*c0.x; acc[1]+=wv*c0.y; acc[2]+=wv*c0.z; acc[3]+=wv*c0.w;
    acc[4]+=wv*c1.x; acc[5]+=wv*c1.y; acc[6]+=wv*c1.z; acc[7]+=wv*c1.w;
  }
  float o[8];
  #pragma unroll
  for (int j=0;j<8;j++) o[j]=acc[j];
  if (ADD){
    float4 a0 = *(const float4*)(addsrc + tok*16 + s8*8);
    float4 a1 = *(const float4*)(addsrc + tok*16 + s8*8+4);
    o[0]+=a0.x; o[1]+=a0.y; o[2]+=a0.z; o[3]+=a0.w;
    o[4]+=a1.x; o[5]+=a1.y; o[6]+=a1.z; o[7]+=a1.w;
  }
  if (DOTANH){
    #pragma unroll
    for (int j=0;j<8;j++) o[j]=tanhf(o[j]);
  }
  float4 r0 = {o[0],o[1],o[2],o[3]}, r1 = {o[4],o[5],o[6],o[7]};
  *(float4*)(dst + tok*16 + s8*8) = r0;
  *(float4*)(dst + tok*16 + s8*8 + 4) = r1;
  if (STATS){
    #pragma unroll
    for (int j=0;j<8;j++){ atomicAdd(&ssum[s8*8+j], o[j]); atomicAdd(&ssq[s8*8+j], o[j]*o[j]); }
    __syncthreads();
    if (t < 16){
      atomicAdd(&stats[t], (double)ssum[t]);
      atomicAdd(&stats[16+t], (double)ssq[t]);
    }
  }
}

// ---------------- delta[m][s] += sum_t wT[m][t] * ALPHA*(Tstar - read)[t][s] ----------------
// thread (tm,ts): owns m in {tm + 16*i, i=0..7}
template<int S>
__global__ __launch_bounds__(256)
void k_delta(const float* __restrict__ wT, const float* __restrict__ tstar,
             const float* __restrict__ rd, float* __restrict__ delta, int T, int KCH){
  constexpr int SUB = 64;
  constexpr int SJ = (S==128)?8:1;
  __shared__ float wl[128*66];
  __shared__ float dl[SUB*S];
  int t = threadIdx.x;
  int tm = t >> 4, ts = t & 15;
  size_t base = (size_t)blockIdx.x * KCH;
  float acc[8][SJ];
  #pragma unroll
  for (int i=0;i<8;i++) for (int j=0;j<SJ;j++) acc[i][j]=0.f;
  for (int c0=0; c0<KCH; c0+=SUB){
    for (int i=t; i<128*16; i+=256){
      int m = i >> 4; int tq = i & 15;
      float4 v = *(const float4*)(wT + (size_t)m*T + base + c0 + tq*4);
      float* wp = &wl[m*66 + tq*4];
      *(float2*)(wp)   = make_float2(v.x, v.y);
      *(float2*)(wp+2) = make_float2(v.z, v.w);
    }
    for (int i=t; i<SUB*S/4; i+=256){
      int tt = i/(S/4); int sq = i%(S/4);
      size_t tok = base + c0 + tt;
      float4 a = *(const float4*)(tstar + tok*S + sq*4);
      float4 r = *(const float4*)(rd + tok*S + sq*4);
      float4 d; d.x = 0.1f*(a.x-r.x); d.y = 0.1f*(a.y-r.y); d.z = 0.1f*(a.z-r.z); d.w = 0.1f*(a.w-r.w);
      *(float4*)(&dl[tt*S + sq*4]) = d;
    }
    __syncthreads();
    for (int tt=0; tt<SUB; ++tt){
      float wv[8];
      #pragma unroll
      for (int i=0;i<8;i++) wv[i] = wl[(tm+16*i)*66 + tt];
      if constexpr (S==128){
        float4 d0 = *(const float4*)(&dl[tt*128 + ts*4]);
        float4 d1 = *(const float4*)(&dl[tt*128 + 64 + ts*4]);
        #pragma unroll
        for (int i=0;i<8;i++){
          acc[i][0] += wv[i]*d0.x; acc[i][1] += wv[i]*d0.y;
          acc[i][2] += wv[i]*d0.z; acc[i][3] += wv[i]*d0.w;
          acc[i][4] += wv[i]*d1.x; acc[i][5] += wv[i]*d1.y;
          acc[i][6] += wv[i]*d1.z; acc[i][7] += wv[i]*d1.w;
        }
      } else {
        float dv = dl[tt*16 + ts];
        #pragma unroll
        for (int i=0;i<8;i++) acc[i][0] += wv[i]*dv;
      }
    }
    __syncthreads();
  }
  if constexpr (S==128){
    #pragma unroll
    for (int i=0;i<8;i++){
      #pragma unroll
      for (int j=0;j<4;j++){
        atomicAdd(&delta[(tm+16*i)*128 + ts*4 + j], acc[i][j]);
        atomicAdd(&delta[(tm+16*i)*128 + 64 + ts*4 + j], acc[i][4+j]);
      }
    }
  } else {
    #pragma unroll
    for (int i=0;i<8;i++)
      atomicAdd(&delta[(tm+16*i)*16 + ts], acc[i][0]);
  }
}

// ---------------- BN finalize ----------------
__global__ void k_bnfin(const double* __restrict__ stats, const float* __restrict__ g,
                        const float* __restrict__ b, float* __restrict__ sc,
                        float* __restrict__ sh, int C, double invT){
  int c = threadIdx.x; if (c >= C) return;
  double mean = stats[c]*invT;
  double var = stats[C+c]*invT - mean*mean;
  if (var < 0.0) var = 0.0;
  double s = (double)g[c] / sqrt(var + 1e-5);
  sc[c] = (float)s; sh[c] = (float)((double)b[c] - mean*s);
}

// ---------------- deconv 4x4 stride2 pad1, CIN=128 NHWC(+bn) -> CO=3 NHWC, silu ----------------
__global__ __launch_bounds__(256)
void k_deconv(const float* __restrict__ in, const float* __restrict__ wd,
              const float* __restrict__ bias, float* __restrict__ out,
              const float* __restrict__ sc, const float* __restrict__ sh){
  __shared__ float lds[2*130*128];
  __shared__ float scl[128], shl[128];
  int t = threadIdx.x;
  int oy = blockIdx.x & 255; int b = blockIdx.x >> 8;
  if (t < 128){ scl[t]=sc[t]; shl[t]=sh[t]; }
  __syncthreads();
  int p = (oy+1)&1;
  int iy_hi = (oy+1-p)>>1;
  for (int r=0;r<2;r++){
    int iy = iy_hi - 1 + r;
    bool valid = (unsigned)iy < 128u;
    const float* rp = in + ((size_t)b*128 + iy)*128*128;
    for (int i=t; i<130*32; i+=256){
      int col=i/32, cq=i%32;
      int ix = col-1;
      float4 v = make_float4(0.f,0.f,0.f,0.f);
      if (valid && (unsigned)ix<128u){
        v = *(const float4*)(rp + (size_t)ix*128 + cq*4);
        v.x = v.x*scl[cq*4+0]+shl[cq*4+0];
        v.y = v.y*scl[cq*4+1]+shl[cq*4+1];
        v.z = v.z*scl[cq*4+2]+shl[cq*4+2];
        v.w = v.w*scl[cq*4+3]+shl[cq*4+3];
      }
      *(float4*)(&lds[(r*130+col)*128 + cq*4]) = v;
    }
  }
  __syncthreads();
  int ox = t;
  int px_ = (ox+1)&1;
  int ix_hi = (ox+1-px_)>>1;
  float acc0=bias[0], acc1=bias[1], acc2=bias[2];
  for (int ry=0; ry<2; ++ry){
    for (int cx=0; cx<2; ++cx){
      int kx = px_ + 2*(1-cx);
      int ix = ix_hi - (1-cx);
      int lcol = ix + 1;
      int ky = p + 2*(1-ry);
      int tap = ky*4 + kx;
      const float* lp = &lds[(ry*130 + lcol)*128];
      const float* wp = wd + (size_t)tap*128*3;
      for (int cq=0; cq<32; ++cq){
        float4 a = *(const float4*)(lp + cq*4);
        float4 w0 = *(const float4*)(wp + cq*12);
        float4 w1 = *(const float4*)(wp + cq*12+4);
        float4 w2 = *(const float4*)(wp + cq*12+8);
        acc0 += a.x*w0.x + a.y*w0.w + a.z*w1.z + a.w*w2.y;
        acc1 += a.x*w0.y + a.y*w1.x + a.z*w1.w + a.w*w2.z;
        acc2 += a.x*w0.z + a.y*w1.y + a.z*w2.x + a.w*w2.w;
      }
    }
  }
  float* op = out + (((size_t)b*256 + oy)*256 + ox)*3;
  op[0]=silu_f(acc0); op[1]=silu_f(acc1); op[2]=silu_f(acc2);
}

// ---------------- final conv 3x3, 3->3, NHWC in -> NCHW out, silu ----------------
__global__ __launch_bounds__(256)
void k_conv33(const float* __restrict__ in, const float* __restrict__ wt,
              const float* __restrict__ bias, float* __restrict__ out){
  int pidx = blockIdx.x*256 + threadIdx.x;
  int b = pidx >> 16; int rem = pidx & 65535;
  int y = rem >> 8, x = rem & 255;
  float a0=bias[0], a1=bias[1], a2=bias[2];
  for (int dy=0;dy<3;dy++){
    int yy=y+dy-1; if((unsigned)yy>=256u) continue;
    for (int dx=0;dx<3;dx++){
      int xx2=x+dx-1; if((unsigned)xx2>=256u) continue;
      const float* ip = in + (((size_t)b*256+yy)*256+xx2)*3;
      #pragma unroll
      for (int ci=0;ci<3;ci++){
        float v = ip[ci];
        const float* wp = wt + (ci*9 + dy*3 + dx)*3;
        a0 += v*wp[0]; a1 += v*wp[1]; a2 += v*wp[2];
      }
    }
  }
  size_t o = (size_t)b*3*65536 + (size_t)y*256 + x;
  out[o]         = silu_f(a0);
  out[o+65536]   = silu_f(a1);
  out[o+2*65536] = silu_f(a2);
}

// ================= host side =================
extern "C" void kernel_launch(void* const* d_in, const int* in_sizes, int n_in,
                              void* d_out, int out_size, void* d_ws, size_t ws_size,
                              hipStream_t stream) {
  const float* x       = (const float*)d_in[0];
  const float* e0n_w1  = (const float*)d_in[1];
  const float* e0n_b1  = (const float*)d_in[2];
  const float* e0n_w2  = (const float*)d_in[3];
  const float* e0n_b2  = (const float*)d_in[4];
  const float* e0s_w1  = (const float*)d_in[5];
  const float* e0s_b1  = (const float*)d_in[6];
  const float* e0s_w2  = (const float*)d_in[7];
  const float* e0s_b2  = (const float*)d_in[8];
  const float* bnn_w1  = (const float*)d_in[9];
  const float* bnn_b1  = (const float*)d_in[10];
  const float* bnn_w2  = (const float*)d_in[11];
  const float* bnn_b2  = (const float*)d_in[12];
  const float* bns_w1  = (const float*)d_in[13];
  const float* bns_b1  = (const float*)d_in[14];
  const float* bns_w2  = (const float*)d_in[15];
  const float* bns_b2  = (const float*)d_in[16];
  const float* d0_wt   = (const float*)d_in[17];
  const float* d0_bt   = (const float*)d_in[18];
  const float* d0_wc   = (const float*)d_in[19];
  const float* d0_bc   = (const float*)d_in[20];
  const float* g0      = (const float*)d_in[21];
  const float* be0     = (const float*)d_in[22];
  const float* gb      = (const float*)d_in[23];
  const float* bb      = (const float*)d_in[24];
  const float* gd      = (const float*)d_in[25];
  const float* bd      = (const float*)d_in[26];
  const float* c0_zhat = (const float*)d_in[27];
  const float* c0_That = (const float*)d_in[28];
  const float* cb_zhat = (const float*)d_in[29];
  const float* cb_That = (const float*)d_in[30];

  char* wsb = (char*)d_ws;
  const size_t SLOT = 33554432ull;
  const size_t R1 = 4*SLOT;
  const size_t R2 = R1 + 16777216ull;
  const size_t R3 = R2 + 4194304ull;
  const size_t R4 = R3 + 33554432ull;
  const size_t WB = R4 + 81920ull;
  const size_t NEED = WB + 1967104ull;
  if (ws_size < NEED) return;

  float* t1    = (float*)(wsb + 0);
  float* w0T   = (float*)(wsb + 0);
  float* u2    = (float*)(wsb + 0);
  float* xt3   = (float*)(wsb + 0);
  float* read0 = (float*)(wsb + SLOT);
  float* w2T   = (float*)(wsb + SLOT);
  float* xt1   = (float*)(wsb + 2*SLOT);
  float* wbT   = (float*)(wsb + 2*SLOT);
  float* u1    = (float*)(wsb + 3*SLOT);
  float* t0    = (float*)(wsb + R1);
  float* bnnb  = (float*)(wsb + R1);
  float* bnsb  = (float*)(wsb + R1 + 4194304ull);
  float* readb = (float*)(wsb + R1 + 8388608ull);
  float* xt2   = (float*)(wsb + R1 + 12582912ull);
  float* e0n   = (float*)(wsb + R2);
  float* y1    = (float*)(wsb + R2);
  float* e0s   = (float*)(wsb + R3);
  float* delta0 = (float*)(wsb + R4);
  float* deltab = (float*)(wsb + R4 + 65536ull);
  double* stats0 = (double*)(wsb + R4 + 73728ull);
  double* statsb = (double*)(wsb + R4 + 75776ull);
  double* statsd = (double*)(wsb + R4 + 76288ull);
  float* sc0 = (float*)(wsb + R4 + 78336ull);
  float* sh0 = (float*)(wsb + R4 + 78848ull);
  float* scb = (float*)(wsb + R4 + 79360ull);
  float* shb = (float*)(wsb + R4 + 79872ull);
  float* scd = (float*)(wsb + R4 + 80384ull);
  float* shd = (float*)(wsb + R4 + 80896ull);
  float* wt_e0n1 = (float*)(wsb + WB);
  float* wt_e0n2 = (float*)(wsb + WB + 2048ull);
  float* wt_e0s1 = (float*)(wsb + WB + 11264ull);
  float* wt_e0s2 = (float*)(wsb + WB + 25088ull);
  float* wt_bnn1 = (float*)(wsb + WB + 614912ull);
  float* wt_bnn2 = (float*)(wsb + WB + 1204736ull);
  float* wt_bns1 = (float*)(wsb + WB + 1278464ull);
  float* wt_bns2 = (float*)(wsb + WB + 1868288ull);
  float* wt_d0c  = (float*)(wsb + WB + 1942016ull);
  float* wd_dec  = (float*)(wsb + WB + 1942528ull);

  const int T = 65536;
  const double invT = 1.0/65536.0;

  k_zero<<<77, 256, 0, stream>>>((float*)(wsb + R4), 19584);

  XArgs xa;
  xa.j[0] = { e0n_w1, wt_e0n1, 3, 16, 432, 0 };
  xa.j[1] = { e0n_w2, wt_e0n2, 16, 16, 2304, 0 };
  xa.j[2] = { e0s_w1, wt_e0s1, 3, 128, 3456, 0 };
  xa.j[3] = { e0s_w2, wt_e0s2, 128, 128, 147456, 0 };
  xa.j[4] = { bnn_w1, wt_bnn1, 128, 128, 147456, 0 };
  xa.j[5] = { bnn_w2, wt_bnn2, 128, 16, 18432, 0 };
  xa.j[6] = { bns_w1, wt_bns1, 128, 128, 147456, 0 };
  xa.j[7] = { bns_w2, wt_bns2, 128, 16, 18432, 0 };
  xa.j[8] = { d0_wc,  wt_d0c,  3, 3, 81, 0 };
  xa.j[9] = { d0_wt,  wd_dec,  128, 3, 6144, 1 };
  k_xform<<<dim3(576,10), 256, 0, stream>>>(xa);

  // encoder stems
  k_conv_cin3<16><<<4096, 256, 0, stream>>>(x, wt_e0n1, e0n_b1, t0);
  k_conv_cin3<128><<<32768, 256, 0, stream>>>(x, wt_e0s1, e0s_b1, t1);
  k_rowconv<16,16,2,128><<<512, 256, 0, stream>>>(t0, wt_e0n2, e0n_b2, e0n, 256, 256);
  k_conv128<2,16,128,8><<<4096, 256, 0, stream>>>(t1, wt_e0s2, e0s_b2, e0s, nullptr, nullptr, 256, 256);

  // memcell 0 write
  k_weights<<<256, 256, 0, stream>>>(e0n, c0_zhat, w0T, nullptr, nullptr, T);
  k_gemm128<false,false,false,false><<<1024, 256, 0, stream>>>(w0T, c0_That, nullptr, nullptr, read0, nullptr, T);
  k_delta<128><<<512, 256, 0, stream>>>(w0T, e0s, read0, delta0, T, 128);
  k_gemm128<true,true,true,false><<<1024, 256, 0, stream>>>(w0T, delta0, nullptr, read0, xt1, stats0, T);
  k_bnfin<<<1, 128, 0, stream>>>(stats0, g0, be0, sc0, sh0, 128, invT);

  // bottleneck branches (bn folded into input load)
  k_conv128<1,32,128,8><<<2048, 256, 0, stream>>>(xt1, wt_bnn1, bnn_b1, u1, sc0, sh0, 128, 128);
  k_conv128<1,64,16,4><<<1024, 256, 0, stream>>>(u1, wt_bnn2, bnn_b2, bnnb, nullptr, nullptr, 128, 128);
  k_conv128<1,32,128,8><<<2048, 256, 0, stream>>>(xt1, wt_bns1, bns_b1, u2, sc0, sh0, 128, 128);
  k_conv128<1,64,16,4><<<1024, 256, 0, stream>>>(u2, wt_bns2, bns_b2, bnsb, nullptr, nullptr, 128, 128);

  // memcell b write
  k_weights<<<256, 256, 0, stream>>>(bnnb, cb_zhat, wbT, nullptr, nullptr, T);
  k_gemm16<false,false,false><<<512, 256, 0, stream>>>(wbT, cb_That, nullptr, readb, nullptr, T);
  k_delta<16><<<512, 256, 0, stream>>>(wbT, bnsb, readb, deltab, T, 128);
  k_gemm16<true,true,true><<<512, 256, 0, stream>>>(wbT, deltab, readb, xt2, statsb, T);
  k_bnfin<<<1, 64, 0, stream>>>(statsb, gb, bb, scb, shb, 16, invT);

  // decoder recall-read against cell 0
  k_weights<<<256, 256, 0, stream>>>(xt2, c0_zhat, w2T, scb, shb, T);
  k_gemm128<false,true,true,true><<<1024, 256, 0, stream>>>(w2T, c0_That, delta0, nullptr, xt3, statsd, T);
  k_bnfin<<<1, 128, 0, stream>>>(statsd, gd, bd, scd, shd, 128, invT);

  // deconv + final conv
  k_deconv<<<1024, 256, 0, stream>>>(xt3, wd_dec, d0_bt, y1, scd, shd);
  k_conv33<<<1024, 256, 0, stream>>>(y1, wt_d0c, d0_bc, (float*)d_out);
}

// Round 5
// 3371.749 us; speedup vs baseline: 1.0172x; 1.0172x over previous
//
#include <hip/hip_runtime.h>
#include <math.h>

#define DEVI __device__ __forceinline__

DEVI float silu_f(float x){ return x / (1.0f + __expf(-x)); }

// ---------------- utility: zero a float region ----------------
__global__ void k_zero(float* p, int n){
  int i = blockIdx.x*256 + threadIdx.x;
  if (i < n) p[i] = 0.f;
}

// ---------------- weight transforms ----------------
// mode 0: OIHW [CO][CI][3][3] -> K-major [ci*9+tap][CO]
// mode 1: OIHW -> tap-major [tap][ci][CO]
// mode 2: deconv [CI=128][CO=3][4][4] -> [tap][ci][co]
struct XJob { const float* src; float* dst; int ci, co, n, mode; };
struct XArgs { XJob j[10]; };

__global__ void k_xform(XArgs a){
  XJob jb = a.j[blockIdx.y];
  int e = blockIdx.x*256 + threadIdx.x;
  if (e >= jb.n) return;
  if (jb.mode == 0){
    int co = e % jb.co; int k = e / jb.co; int ci = k/9; int jj = k - ci*9;
    jb.dst[e] = jb.src[(co*jb.ci + ci)*9 + jj];
  } else if (jb.mode == 1){
    int co = e % jb.co; int r = e / jb.co; int ci = r % jb.ci; int tap = r / jb.ci;
    jb.dst[e] = jb.src[(co*jb.ci + ci)*9 + tap];
  } else {
    int co = e % 3; int r = e/3; int ci = r & 127; int tap = r >> 7;
    int ky = tap >> 2, kx = tap & 3;
    jb.dst[e] = jb.src[((ci*3 + co)*4 + ky)*4 + kx];
  }
}

// ---------------- conv 3x3, CIN=3, NCHW input -> NHWC output, silu ----------------
template<int CO>
__global__ __launch_bounds__(256)
void k_conv_cin3(const float* __restrict__ x, const float* __restrict__ wt,
                 const float* __restrict__ bias, float* __restrict__ out){
  constexpr int CO4 = CO/4;
  constexpr int PPB = 256/CO4;
  int t = threadIdx.x;
  int co4 = t % CO4, pi = t / CO4;
  int p = blockIdx.x*PPB + pi;
  int b = p >> 16;
  int rem = p & 65535;
  int y = rem >> 8, xx = rem & 255;
  float4 acc = *(const float4*)(bias + co4*4);
  #pragma unroll
  for (int ci = 0; ci < 3; ++ci)
    for (int dy = 0; dy < 3; ++dy){
      int yy = y + dy - 1;
      if ((unsigned)yy >= 256u) continue;
      for (int dx = 0; dx < 3; ++dx){
        int xg = xx + dx - 1;
        if ((unsigned)xg >= 256u) continue;
        float v = x[(((size_t)b*3 + ci)*256 + yy)*256 + xg];
        int k = ci*9 + dy*3 + dx;
        float4 w = *(const float4*)(wt + (size_t)k*CO + co4*4);
        acc.x += v*w.x; acc.y += v*w.y; acc.z += v*w.z; acc.w += v*w.w;
      }
    }
  float4 o; o.x = silu_f(acc.x); o.y = silu_f(acc.y); o.z = silu_f(acc.z); o.w = silu_f(acc.w);
  *(float4*)(out + (size_t)p*CO + co4*4) = o;
}

// ---------------- CIN=128 3x3 conv, 2D tile, weight register pipeline ----------------
// Block: R rows x C cols x CO. Weights tap-major [tap][ci][CO].
// Input staged per 32-ci chunk into LDS, pixel stride CPAD=36 (aligned + conflict-free).
template<int STRIDE, int R, int C, int CO, int COPT>
__global__ __launch_bounds__(256, 3)
void k_conv2d(const float* __restrict__ in, const float* __restrict__ wt,
              const float* __restrict__ bias, float* __restrict__ out,
              const float* __restrict__ sc, const float* __restrict__ sh,
              int H_in, int W_in){
  constexpr int IR = R*STRIDE + 2;
  constexpr int IC = C*STRIDE + 2;
  constexpr int COG = CO/COPT;
  constexpr int PG = 256/COG;
  constexpr int PX = (R*C)/PG;
  constexpr int NV = COPT/4;
  constexpr int CPAD = 36;
  __shared__ float lds[IR*IC*CPAD];
  __shared__ float scl[128], shl[128];
  int t = threadIdx.x;
  int cog = t % COG, pg = t / COG;
  const int HO = H_in/STRIDE, WO = W_in/STRIDE;
  const int SEGC = WO / C, NRB = HO / R;
  int bx = blockIdx.x;
  int seg = bx % SEGC; int rb = (bx/SEGC) % NRB; int b = bx/(SEGC*NRB);
  int ry0 = rb*R*STRIDE, cx0 = seg*C*STRIDE;
  bool hasS = (sc != nullptr);
  if (t < 128){ scl[t] = hasS ? sc[t] : 1.f; shl[t] = hasS ? sh[t] : 0.f; }
  float acc[PX][COPT];
  #pragma unroll
  for (int i=0;i<PX;i++)
    #pragma unroll
    for (int v=0;v<NV;v++){
      float4 bv = *(const float4*)(bias + cog*COPT + v*4);
      acc[i][v*4+0]=bv.x; acc[i][v*4+1]=bv.y; acc[i][v*4+2]=bv.z; acc[i][v*4+3]=bv.w;
    }
  int pbase[PX], prow[PX], pcol[PX];
  #pragma unroll
  for (int i=0;i<PX;i++){
    int p = pg + PG*i; int pr = p / C; int pc = p % C;
    prow[i] = pr; pcol[i] = pc;
    pbase[i] = (pr*STRIDE*IC + pc*STRIDE)*CPAD;
  }
  const float* wcog = wt + cog*COPT;
  __syncthreads();
  for (int ck=0; ck<4; ++ck){
    // ---- stage input chunk ----
    for (int e=t; e<IR*IC*8; e+=256){
      int cq = e & 7; int rc = e >> 3; int ic = rc % IC; int ir = rc / IC;
      int gy = ry0 + ir - 1, gx = cx0 + ic - 1;
      float4 v = make_float4(0.f,0.f,0.f,0.f);
      if ((unsigned)gy < (unsigned)H_in && (unsigned)gx < (unsigned)W_in){
        int cb = ck*32 + cq*4;
        v = *(const float4*)(in + (((size_t)b*H_in + gy)*(size_t)W_in + gx)*128 + cb);
        v.x = v.x*scl[cb+0] + shl[cb+0];
        v.y = v.y*scl[cb+1] + shl[cb+1];
        v.z = v.z*scl[cb+2] + shl[cb+2];
        v.w = v.w*scl[cb+3] + shl[cb+3];
      }
      *(float4*)(&lds[(ir*IC+ic)*CPAD + cq*4]) = v;
    }
    __syncthreads();
    // ---- pipelined (tap, ci-quad) loop: 72 iters ----
    float4 wA[4*NV], wB[4*NV];
    auto WLOAD = [&](float4* w, int it){
      int tap = it >> 3, ciq = it & 7;
      const float* wp = wcog + (size_t)(tap*128 + ck*32 + ciq*4)*CO;
      #pragma unroll
      for (int c=0;c<4;c++)
        #pragma unroll
        for (int v=0;v<NV;v++)
          w[c*NV+v] = *(const float4*)(wp + c*CO + v*4);
    };
    auto COMP = [&](float4* w, int it){
      int tap = it >> 3, ciq = it & 7;
      int dy = tap/3, dx = tap - dy*3;
      int off = (dy*IC + dx)*CPAD + ciq*4;
      #pragma unroll
      for (int i=0;i<PX;i++){
        float4 a = *(const float4*)(&lds[pbase[i] + off]);
        #pragma unroll
        for (int c=0;c<4;c++){
          float av = (c==0)?a.x:(c==1)?a.y:(c==2)?a.z:a.w;
          #pragma unroll
          for (int v=0;v<NV;v++){
            float4 wv = w[c*NV+v];
            acc[i][v*4+0] += av*wv.x; acc[i][v*4+1] += av*wv.y;
            acc[i][v*4+2] += av*wv.z; acc[i][v*4+3] += av*wv.w;
          }
        }
      }
    };
    WLOAD(wA, 0);
    for (int it=0; it<72; it+=2){
      WLOAD(wB, it+1);
      COMP(wA, it);
      if (it+2 < 72) WLOAD(wA, it+2);
      COMP(wB, it+1);
    }
    __syncthreads();
  }
  // ---- epilogue ----
  #pragma unroll
  for (int i=0;i<PX;i++){
    int orow = rb*R + prow[i], ocol = seg*C + pcol[i];
    float* op = out + (((size_t)b*HO + orow)*WO + ocol)*CO + cog*COPT;
    #pragma unroll
    for (int v=0;v<NV;v++){
      float4 o;
      o.x = silu_f(acc[i][v*4+0]); o.y = silu_f(acc[i][v*4+1]);
      o.z = silu_f(acc[i][v*4+2]); o.w = silu_f(acc[i][v*4+3]);
      *(float4*)(op + v*4) = o;
    }
  }
}

// ---------------- CIN=16 3x3 stride2 conv (e0n stem), LDS stride 20 ----------------
template<int CIN, int CO, int STRIDE, int PXB>
__global__ __launch_bounds__(256)
void k_rowconv(const float* __restrict__ in, const float* __restrict__ wt,
               const float* __restrict__ bias, float* __restrict__ out,
               int H_in, int W_in){
  constexpr int WT = PXB*STRIDE + 2;
  constexpr int CO8 = CO/8;
  constexpr int PG = 256/CO8;
  constexpr int PPT = PXB/PG;
  constexpr int SEGS = 128/PXB;
  constexpr int LSTR = CIN + 4;
  __shared__ float lds[WT*LSTR];
  int t = threadIdx.x;
  int co8 = t % CO8, pg = t / CO8;
  int blk = blockIdx.x;
  int seg = blk % SEGS; int oy = (blk/SEGS) & 127; int b = blk/(SEGS*128);
  int x0 = seg*PXB;
  float acc[PPT][8];
  {
    float4 b0 = *(const float4*)(bias + co8*8);
    float4 b1 = *(const float4*)(bias + co8*8 + 4);
    #pragma unroll
    for (int i=0;i<PPT;i++){
      acc[i][0]=b0.x; acc[i][1]=b0.y; acc[i][2]=b0.z; acc[i][3]=b0.w;
      acc[i][4]=b1.x; acc[i][5]=b1.y; acc[i][6]=b1.z; acc[i][7]=b1.w;
    }
  }
  const int gx0 = x0*STRIDE - 1;
  for (int dy=0; dy<3; ++dy){
    int iy = oy*STRIDE + dy - 1;
    if ((unsigned)iy < (unsigned)H_in){
      const float* rowp = in + ((size_t)b*H_in + iy)*(size_t)W_in*CIN;
      for (int i = t; i < WT*(CIN/4); i += 256){
        int col = i / (CIN/4); int cq = i % (CIN/4);
        int gx = gx0 + col;
        float4 v = make_float4(0.f,0.f,0.f,0.f);
        if ((unsigned)gx < (unsigned)W_in)
          v = *(const float4*)(rowp + (size_t)gx*CIN + cq*4);
        *(float4*)(&lds[col*LSTR + cq*4]) = v;
      }
      __syncthreads();
      for (int dx=0; dx<3; ++dx){
        for (int cq=0; cq<CIN/4; ++cq){
          float4 a4[PPT];
          #pragma unroll
          for (int i=0;i<PPT;i++){
            int lx = (pg*PPT + i)*STRIDE + dx;
            a4[i] = *(const float4*)(&lds[lx*LSTR + cq*4]);
          }
          const float* wk = wt + ((size_t)(cq*4)*9 + dy*3 + dx)*CO + co8*8;
          #pragma unroll
          for (int cc=0; cc<4; ++cc){
            float4 w0 = *(const float4*)(wk + (size_t)cc*9*CO);
            float4 w1 = *(const float4*)(wk + (size_t)cc*9*CO + 4);
            #pragma unroll
            for (int i=0;i<PPT;i++){
              float av = (cc==0) ? a4[i].x : (cc==1) ? a4[i].y : (cc==2) ? a4[i].z : a4[i].w;
              acc[i][0] += av*w0.x; acc[i][1] += av*w0.y; acc[i][2] += av*w0.z; acc[i][3] += av*w0.w;
              acc[i][4] += av*w1.x; acc[i][5] += av*w1.y; acc[i][6] += av*w1.z; acc[i][7] += av*w1.w;
            }
          }
        }
      }
      __syncthreads();
    }
  }
  #pragma unroll
  for (int i=0;i<PPT;i++){
    int px = x0 + pg*PPT + i;
    float4 o0, o1;
    o0.x = silu_f(acc[i][0]); o0.y = silu_f(acc[i][1]); o0.z = silu_f(acc[i][2]); o0.w = silu_f(acc[i][3]);
    o1.x = silu_f(acc[i][4]); o1.y = silu_f(acc[i][5]); o1.z = silu_f(acc[i][6]); o1.w = silu_f(acc[i][7]);
    float* op = out + (((size_t)b*128 + oy)*128 + px)*CO + co8*8;
    *(float4*)op = o0; *(float4*)(op+4) = o1;
  }
}

// ---------------- memcell weights ----------------
__global__ __launch_bounds__(256)
void k_weights(const float* __restrict__ z, const float* __restrict__ zhat,
               float* __restrict__ wT, const float* __restrict__ sc,
               const float* __restrict__ sh, int T){
  __shared__ float zl[128*16];
  __shared__ float zn[128];
  __shared__ float scl[16], shl[16];
  int t = threadIdx.x;
  if (t < 128){
    float s2 = 0.f;
    #pragma unroll
    for (int j=0;j<16;j++){ float v = zhat[t*16+j]; zl[t*16+j] = v; s2 += v*v; }
    zn[t] = s2;
  }
  if (t < 16){ scl[t] = sc ? sc[t] : 1.f; shl[t] = sh ? sh[t] : 0.f; }
  __syncthreads();
  size_t tok = (size_t)blockIdx.x*256 + t;
  float zr[16];
  #pragma unroll
  for (int q=0;q<4;q++){
    float4 v = *(const float4*)(z + tok*16 + q*4);
    zr[q*4+0] = v.x*scl[q*4+0]+shl[q*4+0];
    zr[q*4+1] = v.y*scl[q*4+1]+shl[q*4+1];
    zr[q*4+2] = v.z*scl[q*4+2]+shl[q*4+2];
    zr[q*4+3] = v.w*scl[q*4+3]+shl[q*4+3];
  }
  float mx = -1e30f;
  for (int m=0;m<128;m++){
    float d=0.f;
    #pragma unroll
    for (int j=0;j<16;j++) d += zr[j]*zl[m*16+j];
    float s = 5.0f*(2.f*d - zn[m]);
    mx = fmaxf(mx, s);
  }
  float sum=0.f;
  for (int m=0;m<128;m++){
    float d=0.f;
    #pragma unroll
    for (int j=0;j<16;j++) d += zr[j]*zl[m*16+j];
    sum += __expf(5.0f*(2.f*d - zn[m]) - mx);
  }
  float inv = 1.f/sum;
  for (int m=0;m<128;m++){
    float d=0.f;
    #pragma unroll
    for (int j=0;j<16;j++) d += zr[j]*zl[m*16+j];
    wT[(size_t)m*T + tok] = __expf(5.0f*(2.f*d - zn[m]) - mx)*inv;
  }
}

// ---------------- S=128 GEMM ----------------
template<bool ADD, bool DOTANH, bool STATS, bool MAT2>
__global__ __launch_bounds__(256)
void k_gemm128(const float* __restrict__ wT, const float* __restrict__ mat1,
               const float* __restrict__ mat2, const float* __restrict__ addsrc,
               float* __restrict__ dst, double* __restrict__ stats, int T){
  __shared__ float4 ml4[128*32];
  __shared__ float ssum[128], ssq[128];
  int t = threadIdx.x;
  if (STATS && t < 128){ ssum[t]=0.f; ssq[t]=0.f; }
  for (int i=t; i < 128*32; i += 256){
    float4 v = ((const float4*)mat1)[i];
    if (MAT2){ float4 u = ((const float4*)mat2)[i]; v.x+=u.x; v.y+=u.y; v.z+=u.z; v.w+=u.w; }
    ml4[i] = v;
  }
  __syncthreads();
  int s16 = t & 15, tg = t >> 4;
  size_t tb = (size_t)blockIdx.x*64;
  float accA[4][4], accB[4][4];
  #pragma unroll
  for (int i=0;i<4;i++) for (int j=0;j<4;j++){ accA[i][j]=0.f; accB[i][j]=0.f; }
  const float* wp = wT + tb + tg*4;
  #pragma unroll 4
  for (int m=0;m<128;m++){
    float4 wv = *(const float4*)(wp + (size_t)m*T);
    float4 c0 = ml4[m*32 + s16];
    float4 c1 = ml4[m*32 + 16 + s16];
    float w[4] = {wv.x,wv.y,wv.z,wv.w};
    #pragma unroll
    for (int i=0;i<4;i++){
      accA[i][0] += w[i]*c0.x; accA[i][1] += w[i]*c0.y; accA[i][2] += w[i]*c0.z; accA[i][3] += w[i]*c0.w;
      accB[i][0] += w[i]*c1.x; accB[i][1] += w[i]*c1.y; accB[i][2] += w[i]*c1.z; accB[i][3] += w[i]*c1.w;
    }
  }
  int colA = s16*4, colB = 64 + s16*4;
  float lsA[4], lqA[4], lsB[4], lqB[4];
  #pragma unroll
  for (int j=0;j<4;j++){ lsA[j]=0.f; lqA[j]=0.f; lsB[j]=0.f; lqB[j]=0.f; }
  #pragma unroll
  for (int i=0;i<4;i++){
    size_t tok = tb + tg*4 + i;
    float oA[4], oB[4];
    #pragma unroll
    for (int j=0;j<4;j++){ oA[j]=accA[i][j]; oB[j]=accB[i][j]; }
    if (ADD){
      float4 a0 = *(const float4*)(addsrc + tok*128 + colA);
      float4 a1 = *(const float4*)(addsrc + tok*128 + colB);
      oA[0]+=a0.x; oA[1]+=a0.y; oA[2]+=a0.z; oA[3]+=a0.w;
      oB[0]+=a1.x; oB[1]+=a1.y; oB[2]+=a1.z; oB[3]+=a1.w;
    }
    if (DOTANH){
      #pragma unroll
      for (int j=0;j<4;j++){ oA[j]=tanhf(oA[j]); oB[j]=tanhf(oB[j]); }
    }
    float4 r0 = {oA[0],oA[1],oA[2],oA[3]}, r1 = {oB[0],oB[1],oB[2],oB[3]};
    *(float4*)(dst + tok*128 + colA) = r0;
    *(float4*)(dst + tok*128 + colB) = r1;
    if (STATS){
      #pragma unroll
      for (int j=0;j<4;j++){
        lsA[j]+=oA[j]; lqA[j]+=oA[j]*oA[j];
        lsB[j]+=oB[j]; lqB[j]+=oB[j]*oB[j];
      }
    }
  }
  if (STATS){
    #pragma unroll
    for (int j=0;j<4;j++){
      atomicAdd(&ssum[colA+j], lsA[j]); atomicAdd(&ssq[colA+j], lqA[j]);
      atomicAdd(&ssum[colB+j], lsB[j]); atomicAdd(&ssq[colB+j], lqB[j]);
    }
    __syncthreads();
    if (t < 128){
      atomicAdd(&stats[t], (double)ssum[t]);
      atomicAdd(&stats[128+t], (double)ssq[t]);
    }
  }
}

// ---------------- S=16 GEMM ----------------
template<bool ADD, bool DOTANH, bool STATS>
__global__ __launch_bounds__(256)
void k_gemm16(const float* __restrict__ wT, const float* __restrict__ mat1,
              const float* __restrict__ addsrc, float* __restrict__ dst,
              double* __restrict__ stats, int T){
  __shared__ float ml[128*16];
  __shared__ float ssum[16], ssq[16];
  int t = threadIdx.x;
  if (STATS && t < 16){ ssum[t]=0.f; ssq[t]=0.f; }
  for (int i=t; i < 128*4; i += 256)
    ((float4*)ml)[i] = ((const float4*)mat1)[i];
  __syncthreads();
  size_t tb = (size_t)blockIdx.x*128;
  int s8 = t & 1, tg = t >> 1;
  float acc[8];
  #pragma unroll
  for (int j=0;j<8;j++) acc[j]=0.f;
  size_t tok = tb + tg;
  const float* wp = wT + tok;
  #pragma unroll 4
  for (int m=0;m<128;m++){
    float wv = wp[(size_t)m*T];
    float4 c0 = *(const float4*)(&ml[m*16 + s8*8]);
    float4 c1 = *(const float4*)(&ml[m*16 + s8*8 + 4]);
    acc[0]+=wv*c0.x; acc[1]+=wv*c0.y; acc[2]+=wv*c0.z; acc[3]+=wv*c0.w;
    acc[4]+=wv*c1.x; acc[5]+=wv*c1.y; acc[6]+=wv*c1.z; acc[7]+=wv*c1.w;
  }
  float o[8];
  #pragma unroll
  for (int j=0;j<8;j++) o[j]=acc[j];
  if (ADD){
    float4 a0 = *(const float4*)(addsrc + tok*16 + s8*8);
    float4 a1 = *(const float4*)(addsrc + tok*16 + s8*8+4);
    o[0]+=a0.x; o[1]+=a0.y; o[2]+=a0.z; o[3]+=a0.w;
    o[4]+=a1.x; o[5]+=a1.y; o[6]+=a1.z; o[7]+=a1.w;
  }
  if (DOTANH){
    #pragma unroll
    for (int j=0;j<8;j++) o[j]=tanhf(o[j]);
  }
  float4 r0 = {o[0],o[1],o[2],o[3]}, r1 = {o[4],o[5],o[6],o[7]};
  *(float4*)(dst + tok*16 + s8*8) = r0;
  *(float4*)(dst + tok*16 + s8*8 + 4) = r1;
  if (STATS){
    #pragma unroll
    for (int j=0;j<8;j++){ atomicAdd(&ssum[s8*8+j], o[j]); atomicAdd(&ssq[s8*8+j], o[j]*o[j]); }
    __syncthreads();
    if (t < 16){
      atomicAdd(&stats[t], (double)ssum[t]);
      atomicAdd(&stats[16+t], (double)ssq[t]);
    }
  }
}

// ---------------- delta[m][s] += sum_t wT[m][t] * ALPHA*(Tstar - read)[t][s] ----------------
template<int S>
__global__ __launch_bounds__(256)
void k_delta(const float* __restrict__ wT, const float* __restrict__ tstar,
             const float* __restrict__ rd, float* __restrict__ delta, int T, int KCH){
  constexpr int SUB = 64;
  constexpr int SJ = (S==128)?8:1;
  __shared__ float wl[128*66];
  __shared__ float dl[SUB*S];
  int t = threadIdx.x;
  int tm = t >> 4, ts = t & 15;
  size_t base = (size_t)blockIdx.x * KCH;
  float acc[8][SJ];
  #pragma unroll
  for (int i=0;i<8;i++) for (int j=0;j<SJ;j++) acc[i][j]=0.f;
  for (int c0=0; c0<KCH; c0+=SUB){
    for (int i=t; i<128*16; i+=256){
      int m = i >> 4; int tq = i & 15;
      float4 v = *(const float4*)(wT + (size_t)m*T + base + c0 + tq*4);
      float* wp = &wl[m*66 + tq*4];
      *(float2*)(wp)   = make_float2(v.x, v.y);
      *(float2*)(wp+2) = make_float2(v.z, v.w);
    }
    for (int i=t; i<SUB*S/4; i+=256){
      int tt = i/(S/4); int sq = i%(S/4);
      size_t tok = base + c0 + tt;
      float4 a = *(const float4*)(tstar + tok*S + sq*4);
      float4 r = *(const float4*)(rd + tok*S + sq*4);
      float4 d; d.x = 0.1f*(a.x-r.x); d.y = 0.1f*(a.y-r.y); d.z = 0.1f*(a.z-r.z); d.w = 0.1f*(a.w-r.w);
      *(float4*)(&dl[tt*S + sq*4]) = d;
    }
    __syncthreads();
    for (int tt=0; tt<SUB; ++tt){
      float wv[8];
      #pragma unroll
      for (int i=0;i<8;i++) wv[i] = wl[(tm+16*i)*66 + tt];
      if constexpr (S==128){
        float4 d0 = *(const float4*)(&dl[tt*128 + ts*4]);
        float4 d1 = *(const float4*)(&dl[tt*128 + 64 + ts*4]);
        #pragma unroll
        for (int i=0;i<8;i++){
          acc[i][0] += wv[i]*d0.x; acc[i][1] += wv[i]*d0.y;
          acc[i][2] += wv[i]*d0.z; acc[i][3] += wv[i]*d0.w;
          acc[i][4] += wv[i]*d1.x; acc[i][5] += wv[i]*d1.y;
          acc[i][6] += wv[i]*d1.z; acc[i][7] += wv[i]*d1.w;
        }
      } else {
        float dv = dl[tt*16 + ts];
        #pragma unroll
        for (int i=0;i<8;i++) acc[i][0] += wv[i]*dv;
      }
    }
    __syncthreads();
  }
  if constexpr (S==128){
    #pragma unroll
    for (int i=0;i<8;i++){
      #pragma unroll
      for (int j=0;j<4;j++){
        atomicAdd(&delta[(tm+16*i)*128 + ts*4 + j], acc[i][j]);
        atomicAdd(&delta[(tm+16*i)*128 + 64 + ts*4 + j], acc[i][4+j]);
      }
    }
  } else {
    #pragma unroll
    for (int i=0;i<8;i++)
      atomicAdd(&delta[(tm+16*i)*16 + ts], acc[i][0]);
  }
}

// ---------------- BN finalize ----------------
__global__ void k_bnfin(const double* __restrict__ stats, const float* __restrict__ g,
                        const float* __restrict__ b, float* __restrict__ sc,
                        float* __restrict__ sh, int C, double invT){
  int c = threadIdx.x; if (c >= C) return;
  double mean = stats[c]*invT;
  double var = stats[C+c]*invT - mean*mean;
  if (var < 0.0) var = 0.0;
  double s = (double)g[c] / sqrt(var + 1e-5);
  sc[c] = (float)s; sh[c] = (float)((double)b[c] - mean*s);
}

// ---------------- deconv 4x4 stride2 pad1, CIN=128 NHWC(+bn) -> CO=3 NHWC, silu ----------------
__global__ __launch_bounds__(256)
void k_deconv(const float* __restrict__ in, const float* __restrict__ wd,
              const float* __restrict__ bias, float* __restrict__ out,
              const float* __restrict__ sc, const float* __restrict__ sh){
  __shared__ float lds[2*130*128];
  __shared__ float scl[128], shl[128];
  int t = threadIdx.x;
  int oy = blockIdx.x & 255; int b = blockIdx.x >> 8;
  if (t < 128){ scl[t]=sc[t]; shl[t]=sh[t]; }
  __syncthreads();
  int p = (oy+1)&1;
  int iy_hi = (oy+1-p)>>1;
  for (int r=0;r<2;r++){
    int iy = iy_hi - 1 + r;
    bool valid = (unsigned)iy < 128u;
    const float* rp = in + ((size_t)b*128 + iy)*128*128;
    for (int i=t; i<130*32; i+=256){
      int col=i/32, cq=i%32;
      int ix = col-1;
      float4 v = make_float4(0.f,0.f,0.f,0.f);
      if (valid && (unsigned)ix<128u){
        v = *(const float4*)(rp + (size_t)ix*128 + cq*4);
        v.x = v.x*scl[cq*4+0]+shl[cq*4+0];
        v.y = v.y*scl[cq*4+1]+shl[cq*4+1];
        v.z = v.z*scl[cq*4+2]+shl[cq*4+2];
        v.w = v.w*scl[cq*4+3]+shl[cq*4+3];
      }
      *(float4*)(&lds[(r*130+col)*128 + cq*4]) = v;
    }
  }
  __syncthreads();
  int ox = t;
  int px_ = (ox+1)&1;
  int ix_hi = (ox+1-px_)>>1;
  float acc0=bias[0], acc1=bias[1], acc2=bias[2];
  for (int ry=0; ry<2; ++ry){
    for (int cx=0; cx<2; ++cx){
      int kx = px_ + 2*(1-cx);
      int ix = ix_hi - (1-cx);
      int lcol = ix + 1;
      int ky = p + 2*(1-ry);
      int tap = ky*4 + kx;
      const float* lp = &lds[(ry*130 + lcol)*128];
      const float* wp = wd + (size_t)tap*128*3;
      for (int cq=0; cq<32; ++cq){
        float4 a = *(const float4*)(lp + cq*4);
        float4 w0 = *(const float4*)(wp + cq*12);
        float4 w1 = *(const float4*)(wp + cq*12+4);
        float4 w2 = *(const float4*)(wp + cq*12+8);
        acc0 += a.x*w0.x + a.y*w0.w + a.z*w1.z + a.w*w2.y;
        acc1 += a.x*w0.y + a.y*w1.x + a.z*w1.w + a.w*w2.z;
        acc2 += a.x*w0.z + a.y*w1.y + a.z*w2.x + a.w*w2.w;
      }
    }
  }
  float* op = out + (((size_t)b*256 + oy)*256 + ox)*3;
  op[0]=silu_f(acc0); op[1]=silu_f(acc1); op[2]=silu_f(acc2);
}

// ---------------- final conv 3x3, 3->3, NHWC in -> NCHW out, silu ----------------
__global__ __launch_bounds__(256)
void k_conv33(const float* __restrict__ in, const float* __restrict__ wt,
              const float* __restrict__ bias, float* __restrict__ out){
  int pidx = blockIdx.x*256 + threadIdx.x;
  int b = pidx >> 16; int rem = pidx & 65535;
  int y = rem >> 8, x = rem & 255;
  float a0=bias[0], a1=bias[1], a2=bias[2];
  for (int dy=0;dy<3;dy++){
    int yy=y+dy-1; if((unsigned)yy>=256u) continue;
    for (int dx=0;dx<3;dx++){
      int xx2=x+dx-1; if((unsigned)xx2>=256u) continue;
      const float* ip = in + (((size_t)b*256+yy)*256+xx2)*3;
      #pragma unroll
      for (int ci=0;ci<3;ci++){
        float v = ip[ci];
        const float* wp = wt + (ci*9 + dy*3 + dx)*3;
        a0 += v*wp[0]; a1 += v*wp[1]; a2 += v*wp[2];
      }
    }
  }
  size_t o = (size_t)b*3*65536 + (size_t)y*256 + x;
  out[o]         = silu_f(a0);
  out[o+65536]   = silu_f(a1);
  out[o+2*65536] = silu_f(a2);
}

// ================= host side =================
extern "C" void kernel_launch(void* const* d_in, const int* in_sizes, int n_in,
                              void* d_out, int out_size, void* d_ws, size_t ws_size,
                              hipStream_t stream) {
  const float* x       = (const float*)d_in[0];
  const float* e0n_w1  = (const float*)d_in[1];
  const float* e0n_b1  = (const float*)d_in[2];
  const float* e0n_w2  = (const float*)d_in[3];
  const float* e0n_b2  = (const float*)d_in[4];
  const float* e0s_w1  = (const float*)d_in[5];
  const float* e0s_b1  = (const float*)d_in[6];
  const float* e0s_w2  = (const float*)d_in[7];
  const float* e0s_b2  = (const float*)d_in[8];
  const float* bnn_w1  = (const float*)d_in[9];
  const float* bnn_b1  = (const float*)d_in[10];
  const float* bnn_w2  = (const float*)d_in[11];
  const float* bnn_b2  = (const float*)d_in[12];
  const float* bns_w1  = (const float*)d_in[13];
  const float* bns_b1  = (const float*)d_in[14];
  const float* bns_w2  = (const float*)d_in[15];
  const float* bns_b2  = (const float*)d_in[16];
  const float* d0_wt   = (const float*)d_in[17];
  const float* d0_bt   = (const float*)d_in[18];
  const float* d0_wc   = (const float*)d_in[19];
  const float* d0_bc   = (const float*)d_in[20];
  const float* g0      = (const float*)d_in[21];
  const float* be0     = (const float*)d_in[22];
  const float* gb      = (const float*)d_in[23];
  const float* bb      = (const float*)d_in[24];
  const float* gd      = (const float*)d_in[25];
  const float* bd      = (const float*)d_in[26];
  const float* c0_zhat = (const float*)d_in[27];
  const float* c0_That = (const float*)d_in[28];
  const float* cb_zhat = (const float*)d_in[29];
  const float* cb_That = (const float*)d_in[30];

  char* wsb = (char*)d_ws;
  const size_t SLOT = 33554432ull;
  const size_t R1 = 4*SLOT;
  const size_t R2 = R1 + 16777216ull;
  const size_t R3 = R2 + 4194304ull;
  const size_t R4 = R3 + 33554432ull;
  const size_t WB = R4 + 81920ull;
  const size_t NEED = WB + 1967104ull;
  if (ws_size < NEED) return;

  float* t1    = (float*)(wsb + 0);
  float* w0T   = (float*)(wsb + 0);
  float* u2    = (float*)(wsb + 0);
  float* xt3   = (float*)(wsb + 0);
  float* read0 = (float*)(wsb + SLOT);
  float* w2T   = (float*)(wsb + SLOT);
  float* xt1   = (float*)(wsb + 2*SLOT);
  float* wbT   = (float*)(wsb + 2*SLOT);
  float* u1    = (float*)(wsb + 3*SLOT);
  float* t0    = (float*)(wsb + R1);
  float* bnnb  = (float*)(wsb + R1);
  float* bnsb  = (float*)(wsb + R1 + 4194304ull);
  float* readb = (float*)(wsb + R1 + 8388608ull);
  float* xt2   = (float*)(wsb + R1 + 12582912ull);
  float* e0n   = (float*)(wsb + R2);
  float* y1    = (float*)(wsb + R2);
  float* e0s   = (float*)(wsb + R3);
  float* delta0 = (float*)(wsb + R4);
  float* deltab = (float*)(wsb + R4 + 65536ull);
  double* stats0 = (double*)(wsb + R4 + 73728ull);
  double* statsb = (double*)(wsb + R4 + 75776ull);
  double* statsd = (double*)(wsb + R4 + 76288ull);
  float* sc0 = (float*)(wsb + R4 + 78336ull);
  float* sh0 = (float*)(wsb + R4 + 78848ull);
  float* scb = (float*)(wsb + R4 + 79360ull);
  float* shb = (float*)(wsb + R4 + 79872ull);
  float* scd = (float*)(wsb + R4 + 80384ull);
  float* shd = (float*)(wsb + R4 + 80896ull);
  float* wt_e0n1 = (float*)(wsb + WB);
  float* wt_e0n2 = (float*)(wsb + WB + 2048ull);
  float* wt_e0s1 = (float*)(wsb + WB + 11264ull);
  float* wt_e0s2 = (float*)(wsb + WB + 25088ull);
  float* wt_bnn1 = (float*)(wsb + WB + 614912ull);
  float* wt_bnn2 = (float*)(wsb + WB + 1204736ull);
  float* wt_bns1 = (float*)(wsb + WB + 1278464ull);
  float* wt_bns2 = (float*)(wsb + WB + 1868288ull);
  float* wt_d0c  = (float*)(wsb + WB + 1942016ull);
  float* wd_dec  = (float*)(wsb + WB + 1942528ull);

  const int T = 65536;
  const double invT = 1.0/65536.0;

  k_zero<<<77, 256, 0, stream>>>((float*)(wsb + R4), 19584);

  XArgs xa;
  xa.j[0] = { e0n_w1, wt_e0n1, 3, 16, 432, 0 };
  xa.j[1] = { e0n_w2, wt_e0n2, 16, 16, 2304, 0 };
  xa.j[2] = { e0s_w1, wt_e0s1, 3, 128, 3456, 0 };
  xa.j[3] = { e0s_w2, wt_e0s2, 128, 128, 147456, 1 };
  xa.j[4] = { bnn_w1, wt_bnn1, 128, 128, 147456, 1 };
  xa.j[5] = { bnn_w2, wt_bnn2, 128, 16, 18432, 1 };
  xa.j[6] = { bns_w1, wt_bns1, 128, 128, 147456, 1 };
  xa.j[7] = { bns_w2, wt_bns2, 128, 16, 18432, 1 };
  xa.j[8] = { d0_wc,  wt_d0c,  3, 3, 81, 0 };
  xa.j[9] = { d0_wt,  wd_dec,  128, 3, 6144, 2 };
  k_xform<<<dim3(576,10), 256, 0, stream>>>(xa);

  // encoder stems
  k_conv_cin3<16><<<4096, 256, 0, stream>>>(x, wt_e0n1, e0n_b1, t0);
  k_conv_cin3<128><<<32768, 256, 0, stream>>>(x, wt_e0s1, e0s_b1, t1);
  k_rowconv<16,16,2,128><<<512, 256, 0, stream>>>(t0, wt_e0n2, e0n_b2, e0n, 256, 256);
  // e0s conv2: stride2, tile 4x16, grid = (128/16)*(128/4)*4 = 1024
  k_conv2d<2,4,16,128,8><<<1024, 256, 0, stream>>>(t1, wt_e0s2, e0s_b2, e0s, nullptr, nullptr, 256, 256);

  // memcell 0 write
  k_weights<<<256, 256, 0, stream>>>(e0n, c0_zhat, w0T, nullptr, nullptr, T);
  k_gemm128<false,false,false,false><<<1024, 256, 0, stream>>>(w0T, c0_That, nullptr, nullptr, read0, nullptr, T);
  k_delta<128><<<512, 256, 0, stream>>>(w0T, e0s, read0, delta0, T, 128);
  k_gemm128<true,true,true,false><<<1024, 256, 0, stream>>>(w0T, delta0, nullptr, read0, xt1, stats0, T);
  k_bnfin<<<1, 128, 0, stream>>>(stats0, g0, be0, sc0, sh0, 128, invT);

  // bottleneck branches (bn folded into staging): tile 4x32, grid = 4*32*4 = 512
  k_conv2d<1,4,32,128,8><<<512, 256, 0, stream>>>(xt1, wt_bnn1, bnn_b1, u1, sc0, sh0, 128, 128);
  k_conv2d<1,4,32,16,8><<<512, 256, 0, stream>>>(u1, wt_bnn2, bnn_b2, bnnb, nullptr, nullptr, 128, 128);
  k_conv2d<1,4,32,128,8><<<512, 256, 0, stream>>>(xt1, wt_bns1, bns_b1, u2, sc0, sh0, 128, 128);
  k_conv2d<1,4,32,16,8><<<512, 256, 0, stream>>>(u2, wt_bns2, bns_b2, bnsb, nullptr, nullptr, 128, 128);

  // memcell b write
  k_weights<<<256, 256, 0, stream>>>(bnnb, cb_zhat, wbT, nullptr, nullptr, T);
  k_gemm16<false,false,false><<<512, 256, 0, stream>>>(wbT, cb_That, nullptr, readb, nullptr, T);
  k_delta<16><<<512, 256, 0, stream>>>(wbT, bnsb, readb, deltab, T, 128);
  k_gemm16<true,true,true><<<512, 256, 0, stream>>>(wbT, deltab, readb, xt2, statsb, T);
  k_bnfin<<<1, 64, 0, stream>>>(statsb, gb, bb, scb, shb, 16, invT);

  // decoder recall-read against cell 0
  k_weights<<<256, 256, 0, stream>>>(xt2, c0_zhat, w2T, scb, shb, T);
  k_gemm128<false,true,true,true><<<1024, 256, 0, stream>>>(w2T, c0_That, delta0, nullptr, xt3, statsd, T);
  k_bnfin<<<1, 128, 0, stream>>>(statsd, gd, bd, scd, shd, 128, invT);

  // deconv + final conv
  k_deconv<<<1024, 256, 0, stream>>>(xt3, wd_dec, d0_bt, y1, scd, shd);
  k_conv33<<<1024, 256, 0, stream>>>(y1, wt_d0c, d0_bc, (float*)d_out);
}

// Round 7
// 2007.204 us; speedup vs baseline: 1.7087x; 1.6798x over previous
//
#include <hip/hip_runtime.h>
#include <math.h>

#define DEVI __device__ __forceinline__

DEVI float silu_f(float x){ return x / (1.0f + __expf(-x)); }

// ---------------- utility: zero a float region ----------------
__global__ void k_zero(float* p, int n){
  int i = blockIdx.x*256 + threadIdx.x;
  if (i < n) p[i] = 0.f;
}

// ---------------- weight transforms ----------------
// mode 0: OIHW [CO][CI][3][3] -> K-major [ci*9+tap][CO]
// mode 1: OIHW -> tap-major [tap][ci][CO]
// mode 2: deconv [CI=128][CO=3][4][4] -> [tap][ci][co]
struct XJob { const float* src; float* dst; int ci, co, n, mode; };
struct XArgs { XJob j[10]; };

__global__ void k_xform(XArgs a){
  XJob jb = a.j[blockIdx.y];
  int e = blockIdx.x*256 + threadIdx.x;
  if (e >= jb.n) return;
  if (jb.mode == 0){
    int co = e % jb.co; int k = e / jb.co; int ci = k/9; int jj = k - ci*9;
    jb.dst[e] = jb.src[(co*jb.ci + ci)*9 + jj];
  } else if (jb.mode == 1){
    int co = e % jb.co; int r = e / jb.co; int ci = r % jb.ci; int tap = r / jb.ci;
    jb.dst[e] = jb.src[(co*jb.ci + ci)*9 + tap];
  } else {
    int co = e % 3; int r = e/3; int ci = r & 127; int tap = r >> 7;
    int ky = tap >> 2, kx = tap & 3;
    jb.dst[e] = jb.src[((ci*3 + co)*4 + ky)*4 + kx];
  }
}

// ---------------- conv 3x3, CIN=3, NCHW input -> NHWC output, silu ----------------
template<int CO>
__global__ __launch_bounds__(256)
void k_conv_cin3(const float* __restrict__ x, const float* __restrict__ wt,
                 const float* __restrict__ bias, float* __restrict__ out){
  constexpr int CO4 = CO/4;
  constexpr int PPB = 256/CO4;
  int t = threadIdx.x;
  int co4 = t % CO4, pi = t / CO4;
  int p = blockIdx.x*PPB + pi;
  int b = p >> 16;
  int rem = p & 65535;
  int y = rem >> 8, xx = rem & 255;
  float4 acc = *(const float4*)(bias + co4*4);
  #pragma unroll
  for (int ci = 0; ci < 3; ++ci)
    for (int dy = 0; dy < 3; ++dy){
      int yy = y + dy - 1;
      if ((unsigned)yy >= 256u) continue;
      for (int dx = 0; dx < 3; ++dx){
        int xg = xx + dx - 1;
        if ((unsigned)xg >= 256u) continue;
        float v = x[(((size_t)b*3 + ci)*256 + yy)*256 + xg];
        int k = ci*9 + dy*3 + dx;
        float4 w = *(const float4*)(wt + (size_t)k*CO + co4*4);
        acc.x += v*w.x; acc.y += v*w.y; acc.z += v*w.z; acc.w += v*w.w;
      }
    }
  float4 o; o.x = silu_f(acc.x); o.y = silu_f(acc.y); o.z = silu_f(acc.z); o.w = silu_f(acc.w);
  *(float4*)(out + (size_t)p*CO + co4*4) = o;
}

// ---------------- CIN=128 3x3 conv, LDS-staged weights, pure LDS->FMA hot loop ----------------
// weights tap-major [tap][ci][CO]; staged per (ck,dy) as [dx][ci32][CO] rows padded to CO+4.
// lane map: cog = t/PG (wave-broadcast weight reads), pg = t%PG (consecutive pixels).
template<int STRIDE, int R, int C, int CO, int COPT>
__global__ __launch_bounds__(256, 2)
void k_conv3(const float* __restrict__ in, const float* __restrict__ wt,
             const float* __restrict__ bias, float* __restrict__ out,
             const float* __restrict__ sc, const float* __restrict__ sh,
             int H_in, int W_in){
  constexpr int IR = R*STRIDE + 2;
  constexpr int IC = C*STRIDE + 2;
  constexpr int COG = CO/COPT;
  constexpr int PG = 256/COG;
  constexpr int PX = (R*C)/PG;
  constexpr int NV = COPT/4;
  constexpr int CPAD = 36;
  constexpr int WSTR = CO + 4;
  __shared__ float xin[IR*IC*CPAD];
  __shared__ float wl[3*32*WSTR];
  __shared__ float scl[128], shl[128];
  int t = threadIdx.x;
  int cog = t / PG, pg = t % PG;
  const int HO = H_in/STRIDE, WO = W_in/STRIDE;
  const int SEGC = WO / C, NRB = HO / R;
  int bx = blockIdx.x;
  int seg = bx % SEGC; int rb = (bx/SEGC) % NRB; int b = bx/(SEGC*NRB);
  int ry0 = rb*R*STRIDE, cx0 = seg*C*STRIDE;
  bool hasS = (sc != nullptr);
  if (t < 128){ scl[t] = hasS ? sc[t] : 1.f; shl[t] = hasS ? sh[t] : 0.f; }
  float acc[PX][COPT];
  #pragma unroll
  for (int i=0;i<PX;i++)
    #pragma unroll
    for (int v=0;v<NV;v++){
      float4 bv = *(const float4*)(bias + cog*COPT + v*4);
      acc[i][v*4+0]=bv.x; acc[i][v*4+1]=bv.y; acc[i][v*4+2]=bv.z; acc[i][v*4+3]=bv.w;
    }
  int pbase[PX], prow[PX], pcol[PX];
  #pragma unroll
  for (int i=0;i<PX;i++){
    int p = pg + PG*i; int pr = p / C; int pc = p % C;
    prow[i] = pr; pcol[i] = pc;
    pbase[i] = (pr*STRIDE*IC + pc*STRIDE)*CPAD;
  }
  for (int ck=0; ck<4; ++ck){
    __syncthreads();   // prior compute done before overwriting xin
    // ---- stage input chunk (32 ci) ----
    for (int e=t; e<IR*IC*8; e+=256){
      int cq = e & 7; int rc = e >> 3; int ic = rc % IC; int ir = rc / IC;
      int gy = ry0 + ir - 1, gx = cx0 + ic - 1;
      float4 v = make_float4(0.f,0.f,0.f,0.f);
      if ((unsigned)gy < (unsigned)H_in && (unsigned)gx < (unsigned)W_in){
        int cb = ck*32 + cq*4;
        v = *(const float4*)(in + (((size_t)b*H_in + gy)*(size_t)W_in + gx)*128 + cb);
        v.x = v.x*scl[cb+0] + shl[cb+0];
        v.y = v.y*scl[cb+1] + shl[cb+1];
        v.z = v.z*scl[cb+2] + shl[cb+2];
        v.w = v.w*scl[cb+3] + shl[cb+3];
      }
      *(float4*)(&xin[rc*CPAD + cq*4]) = v;
    }
    for (int dy=0; dy<3; ++dy){
      if (dy > 0) __syncthreads();  // prior dy compute done before overwriting wl
      // ---- stage weights for (ck, dy): 3 taps x 32 ci x CO ----
      for (int e=t; e<3*32*(CO/4); e+=256){
        int co4 = e % (CO/4); int r = e / (CO/4); int ci = r % 32; int dx = r / 32;
        float4 wv = *(const float4*)(wt + ((size_t)((dy*3+dx)*128 + ck*32 + ci))*CO + co4*4);
        *(float4*)(&wl[(dx*32+ci)*WSTR + co4*4]) = wv;
      }
      __syncthreads();  // staging visible
      // ---- hot loop: pure LDS ----
      #pragma unroll
      for (int dx=0; dx<3; ++dx){
        #pragma unroll 2
        for (int ciq=0; ciq<8; ++ciq){
          float4 a4[PX];
          #pragma unroll
          for (int i=0;i<PX;i++)
            a4[i] = *(const float4*)(&xin[pbase[i] + (dy*IC + dx)*CPAD + ciq*4]);
          #pragma unroll
          for (int c=0;c<4;c++){
            const float* wrow = &wl[(dx*32 + ciq*4 + c)*WSTR + cog*COPT];
            float4 w0 = *(const float4*)(wrow);
            float4 w1;
            if (NV==2) w1 = *(const float4*)(wrow + 4);
            #pragma unroll
            for (int i=0;i<PX;i++){
              float av = (c==0)?a4[i].x:(c==1)?a4[i].y:(c==2)?a4[i].z:a4[i].w;
              acc[i][0] += av*w0.x; acc[i][1] += av*w0.y; acc[i][2] += av*w0.z; acc[i][3] += av*w0.w;
              if (NV==2){
                acc[i][4] += av*w1.x; acc[i][5] += av*w1.y; acc[i][6] += av*w1.z; acc[i][7] += av*w1.w;
              }
            }
          }
        }
      }
    }
  }
  // ---- epilogue ----
  #pragma unroll
  for (int i=0;i<PX;i++){
    int orow = rb*R + prow[i], ocol = seg*C + pcol[i];
    float* op = out + (((size_t)b*HO + orow)*WO + ocol)*CO + cog*COPT;
    #pragma unroll
    for (int v=0;v<NV;v++){
      float4 o;
      o.x = silu_f(acc[i][v*4+0]); o.y = silu_f(acc[i][v*4+1]);
      o.z = silu_f(acc[i][v*4+2]); o.w = silu_f(acc[i][v*4+3]);
      *(float4*)(op + v*4) = o;
    }
  }
}

// ---------------- CIN=16 3x3 stride2 conv (e0n stem), LDS stride 20 ----------------
template<int CIN, int CO, int STRIDE, int PXB>
__global__ __launch_bounds__(256)
void k_rowconv(const float* __restrict__ in, const float* __restrict__ wt,
               const float* __restrict__ bias, float* __restrict__ out,
               int H_in, int W_in){
  constexpr int WT = PXB*STRIDE + 2;
  constexpr int CO8 = CO/8;
  constexpr int PG = 256/CO8;
  constexpr int PPT = PXB/PG;
  constexpr int SEGS = 128/PXB;
  constexpr int LSTR = CIN + 4;
  __shared__ float lds[WT*LSTR];
  int t = threadIdx.x;
  int co8 = t % CO8, pg = t / CO8;
  int blk = blockIdx.x;
  int seg = blk % SEGS; int oy = (blk/SEGS) & 127; int b = blk/(SEGS*128);
  int x0 = seg*PXB;
  float acc[PPT][8];
  {
    float4 b0 = *(const float4*)(bias + co8*8);
    float4 b1 = *(const float4*)(bias + co8*8 + 4);
    #pragma unroll
    for (int i=0;i<PPT;i++){
      acc[i][0]=b0.x; acc[i][1]=b0.y; acc[i][2]=b0.z; acc[i][3]=b0.w;
      acc[i][4]=b1.x; acc[i][5]=b1.y; acc[i][6]=b1.z; acc[i][7]=b1.w;
    }
  }
  const int gx0 = x0*STRIDE - 1;
  for (int dy=0; dy<3; ++dy){
    int iy = oy*STRIDE + dy - 1;
    if ((unsigned)iy < (unsigned)H_in){
      const float* rowp = in + ((size_t)b*H_in + iy)*(size_t)W_in*CIN;
      for (int i = t; i < WT*(CIN/4); i += 256){
        int col = i / (CIN/4); int cq = i % (CIN/4);
        int gx = gx0 + col;
        float4 v = make_float4(0.f,0.f,0.f,0.f);
        if ((unsigned)gx < (unsigned)W_in)
          v = *(const float4*)(rowp + (size_t)gx*CIN + cq*4);
        *(float4*)(&lds[col*LSTR + cq*4]) = v;
      }
      __syncthreads();
      for (int dx=0; dx<3; ++dx){
        for (int cq=0; cq<CIN/4; ++cq){
          float4 a4[PPT];
          #pragma unroll
          for (int i=0;i<PPT;i++){
            int lx = (pg*PPT + i)*STRIDE + dx;
            a4[i] = *(const float4*)(&lds[lx*LSTR + cq*4]);
          }
          const float* wk = wt + ((size_t)(cq*4)*9 + dy*3 + dx)*CO + co8*8;
          #pragma unroll
          for (int cc=0; cc<4; ++cc){
            float4 w0 = *(const float4*)(wk + (size_t)cc*9*CO);
            float4 w1 = *(const float4*)(wk + (size_t)cc*9*CO + 4);
            #pragma unroll
            for (int i=0;i<PPT;i++){
              float av = (cc==0) ? a4[i].x : (cc==1) ? a4[i].y : (cc==2) ? a4[i].z : a4[i].w;
              acc[i][0] += av*w0.x; acc[i][1] += av*w0.y; acc[i][2] += av*w0.z; acc[i][3] += av*w0.w;
              acc[i][4] += av*w1.x; acc[i][5] += av*w1.y; acc[i][6] += av*w1.z; acc[i][7] += av*w1.w;
            }
          }
        }
      }
      __syncthreads();
    }
  }
  #pragma unroll
  for (int i=0;i<PPT;i++){
    int px = x0 + pg*PPT + i;
    float4 o0, o1;
    o0.x = silu_f(acc[i][0]); o0.y = silu_f(acc[i][1]); o0.z = silu_f(acc[i][2]); o0.w = silu_f(acc[i][3]);
    o1.x = silu_f(acc[i][4]); o1.y = silu_f(acc[i][5]); o1.z = silu_f(acc[i][6]); o1.w = silu_f(acc[i][7]);
    float* op = out + (((size_t)b*128 + oy)*128 + px)*CO + co8*8;
    *(float4*)op = o0; *(float4*)(op+4) = o1;
  }
}

// ---------------- memcell weights ----------------
__global__ __launch_bounds__(256)
void k_weights(const float* __restrict__ z, const float* __restrict__ zhat,
               float* __restrict__ wT, const float* __restrict__ sc,
               const float* __restrict__ sh, int T){
  __shared__ float zl[128*16];
  __shared__ float zn[128];
  __shared__ float scl[16], shl[16];
  int t = threadIdx.x;
  if (t < 128){
    float s2 = 0.f;
    #pragma unroll
    for (int j=0;j<16;j++){ float v = zhat[t*16+j]; zl[t*16+j] = v; s2 += v*v; }
    zn[t] = s2;
  }
  if (t < 16){ scl[t] = sc ? sc[t] : 1.f; shl[t] = sh ? sh[t] : 0.f; }
  __syncthreads();
  size_t tok = (size_t)blockIdx.x*256 + t;
  float zr[16];
  #pragma unroll
  for (int q=0;q<4;q++){
    float4 v = *(const float4*)(z + tok*16 + q*4);
    zr[q*4+0] = v.x*scl[q*4+0]+shl[q*4+0];
    zr[q*4+1] = v.y*scl[q*4+1]+shl[q*4+1];
    zr[q*4+2] = v.z*scl[q*4+2]+shl[q*4+2];
    zr[q*4+3] = v.w*scl[q*4+3]+shl[q*4+3];
  }
  float mx = -1e30f;
  for (int m=0;m<128;m++){
    float d=0.f;
    #pragma unroll
    for (int j=0;j<16;j++) d += zr[j]*zl[m*16+j];
    float s = 5.0f*(2.f*d - zn[m]);
    mx = fmaxf(mx, s);
  }
  float sum=0.f;
  for (int m=0;m<128;m++){
    float d=0.f;
    #pragma unroll
    for (int j=0;j<16;j++) d += zr[j]*zl[m*16+j];
    sum += __expf(5.0f*(2.f*d - zn[m]) - mx);
  }
  float inv = 1.f/sum;
  for (int m=0;m<128;m++){
    float d=0.f;
    #pragma unroll
    for (int j=0;j<16;j++) d += zr[j]*zl[m*16+j];
    wT[(size_t)m*T + tok] = __expf(5.0f*(2.f*d - zn[m]) - mx)*inv;
  }
}

// ---------------- S=128 GEMM ----------------
template<bool ADD, bool DOTANH, bool STATS, bool MAT2>
__global__ __launch_bounds__(256)
void k_gemm128(const float* __restrict__ wT, const float* __restrict__ mat1,
               const float* __restrict__ mat2, const float* __restrict__ addsrc,
               float* __restrict__ dst, double* __restrict__ stats, int T){
  __shared__ float4 ml4[128*32];
  __shared__ float ssum[128], ssq[128];
  int t = threadIdx.x;
  if (STATS && t < 128){ ssum[t]=0.f; ssq[t]=0.f; }
  for (int i=t; i < 128*32; i += 256){
    float4 v = ((const float4*)mat1)[i];
    if (MAT2){ float4 u = ((const float4*)mat2)[i]; v.x+=u.x; v.y+=u.y; v.z+=u.z; v.w+=u.w; }
    ml4[i] = v;
  }
  __syncthreads();
  int s16 = t & 15, tg = t >> 4;
  size_t tb = (size_t)blockIdx.x*64;
  float accA[4][4], accB[4][4];
  #pragma unroll
  for (int i=0;i<4;i++) for (int j=0;j<4;j++){ accA[i][j]=0.f; accB[i][j]=0.f; }
  const float* wp = wT + tb + tg*4;
  #pragma unroll 4
  for (int m=0;m<128;m++){
    float4 wv = *(const float4*)(wp + (size_t)m*T);
    float4 c0 = ml4[m*32 + s16];
    float4 c1 = ml4[m*32 + 16 + s16];
    float w[4] = {wv.x,wv.y,wv.z,wv.w};
    #pragma unroll
    for (int i=0;i<4;i++){
      accA[i][0] += w[i]*c0.x; accA[i][1] += w[i]*c0.y; accA[i][2] += w[i]*c0.z; accA[i][3] += w[i]*c0.w;
      accB[i][0] += w[i]*c1.x; accB[i][1] += w[i]*c1.y; accB[i][2] += w[i]*c1.z; accB[i][3] += w[i]*c1.w;
    }
  }
  int colA = s16*4, colB = 64 + s16*4;
  float lsA[4], lqA[4], lsB[4], lqB[4];
  #pragma unroll
  for (int j=0;j<4;j++){ lsA[j]=0.f; lqA[j]=0.f; lsB[j]=0.f; lqB[j]=0.f; }
  #pragma unroll
  for (int i=0;i<4;i++){
    size_t tok = tb + tg*4 + i;
    float oA[4], oB[4];
    #pragma unroll
    for (int j=0;j<4;j++){ oA[j]=accA[i][j]; oB[j]=accB[i][j]; }
    if (ADD){
      float4 a0 = *(const float4*)(addsrc + tok*128 + colA);
      float4 a1 = *(const float4*)(addsrc + tok*128 + colB);
      oA[0]+=a0.x; oA[1]+=a0.y; oA[2]+=a0.z; oA[3]+=a0.w;
      oB[0]+=a1.x; oB[1]+=a1.y; oB[2]+=a1.z; oB[3]+=a1.w;
    }
    if (DOTANH){
      #pragma unroll
      for (int j=0;j<4;j++){ oA[j]=tanhf(oA[j]); oB[j]=tanhf(oB[j]); }
    }
    float4 r0 = {oA[0],oA[1],oA[2],oA[3]}, r1 = {oB[0],oB[1],oB[2],oB[3]};
    *(float4*)(dst + tok*128 + colA) = r0;
    *(float4*)(dst + tok*128 + colB) = r1;
    if (STATS){
      #pragma unroll
      for (int j=0;j<4;j++){
        lsA[j]+=oA[j]; lqA[j]+=oA[j]*oA[j];
        lsB[j]+=oB[j]; lqB[j]+=oB[j]*oB[j];
      }
    }
  }
  if (STATS){
    #pragma unroll
    for (int j=0;j<4;j++){
      atomicAdd(&ssum[colA+j], lsA[j]); atomicAdd(&ssq[colA+j], lqA[j]);
      atomicAdd(&ssum[colB+j], lsB[j]); atomicAdd(&ssq[colB+j], lqB[j]);
    }
    __syncthreads();
    if (t < 128){
      atomicAdd(&stats[t], (double)ssum[t]);
      atomicAdd(&stats[128+t], (double)ssq[t]);
    }
  }
}

// ---------------- S=16 GEMM ----------------
template<bool ADD, bool DOTANH, bool STATS>
__global__ __launch_bounds__(256)
void k_gemm16(const float* __restrict__ wT, const float* __restrict__ mat1,
              const float* __restrict__ addsrc, float* __restrict__ dst,
              double* __restrict__ stats, int T){
  __shared__ float ml[128*16];
  __shared__ float ssum[16], ssq[16];
  int t = threadIdx.x;
  if (STATS && t < 16){ ssum[t]=0.f; ssq[t]=0.f; }
  for (int i=t; i < 128*4; i += 256)
    ((float4*)ml)[i] = ((const float4*)mat1)[i];
  __syncthreads();
  size_t tb = (size_t)blockIdx.x*128;
  int s8 = t & 1, tg = t >> 1;
  float acc[8];
  #pragma unroll
  for (int j=0;j<8;j++) acc[j]=0.f;
  size_t tok = tb + tg;
  const float* wp = wT + tok;
  #pragma unroll 4
  for (int m=0;m<128;m++){
    float wv = wp[(size_t)m*T];
    float4 c0 = *(const float4*)(&ml[m*16 + s8*8]);
    float4 c1 = *(const float4*)(&ml[m*16 + s8*8 + 4]);
    acc[0]+=wv*c0.x; acc[1]+=wv*c0.y; acc[2]+=wv*c0.z; acc[3]+=wv*c0.w;
    acc[4]+=wv*c1.x; acc[5]+=wv*c1.y; acc[6]+=wv*c1.z; acc[7]+=wv*c1.w;
  }
  float o[8];
  #pragma unroll
  for (int j=0;j<8;j++) o[j]=acc[j];
  if (ADD){
    float4 a0 = *(const float4*)(addsrc + tok*16 + s8*8);
    float4 a1 = *(const float4*)(addsrc + tok*16 + s8*8+4);
    o[0]+=a0.x; o[1]+=a0.y; o[2]+=a0.z; o[3]+=a0.w;
    o[4]+=a1.x; o[5]+=a1.y; o[6]+=a1.z; o[7]+=a1.w;
  }
  if (DOTANH){
    #pragma unroll
    for (int j=0;j<8;j++) o[j]=tanhf(o[j]);
  }
  float4 r0 = {o[0],o[1],o[2],o[3]}, r1 = {o[4],o[5],o[6],o[7]};
  *(float4*)(dst + tok*16 + s8*8) = r0;
  *(float4*)(dst + tok*16 + s8*8 + 4) = r1;
  if (STATS){
    #pragma unroll
    for (int j=0;j<8;j++){ atomicAdd(&ssum[s8*8+j], o[j]); atomicAdd(&ssq[s8*8+j], o[j]*o[j]); }
    __syncthreads();
    if (t < 16){
      atomicAdd(&stats[t], (double)ssum[t]);
      atomicAdd(&stats[16+t], (double)ssq[t]);
    }
  }
}

// ---------------- delta[m][s] += sum_t wT[m][t] * ALPHA*(Tstar - read)[t][s] ----------------
template<int S>
__global__ __launch_bounds__(256)
void k_delta(const float* __restrict__ wT, const float* __restrict__ tstar,
             const float* __restrict__ rd, float* __restrict__ delta, int T, int KCH){
  constexpr int SUB = 64;
  constexpr int SJ = (S==128)?8:1;
  __shared__ float wl[128*66];
  __shared__ float dl[SUB*S];
  int t = threadIdx.x;
  int tm = t >> 4, ts = t & 15;
  size_t base = (size_t)blockIdx.x * KCH;
  float acc[8][SJ];
  #pragma unroll
  for (int i=0;i<8;i++) for (int j=0;j<SJ;j++) acc[i][j]=0.f;
  for (int c0=0; c0<KCH; c0+=SUB){
    for (int i=t; i<128*16; i+=256){
      int m = i >> 4; int tq = i & 15;
      float4 v = *(const float4*)(wT + (size_t)m*T + base + c0 + tq*4);
      float* wp = &wl[m*66 + tq*4];
      *(float2*)(wp)   = make_float2(v.x, v.y);
      *(float2*)(wp+2) = make_float2(v.z, v.w);
    }
    for (int i=t; i<SUB*S/4; i+=256){
      int tt = i/(S/4); int sq = i%(S/4);
      size_t tok = base + c0 + tt;
      float4 a = *(const float4*)(tstar + tok*S + sq*4);
      float4 r = *(const float4*)(rd + tok*S + sq*4);
      float4 d; d.x = 0.1f*(a.x-r.x); d.y = 0.1f*(a.y-r.y); d.z = 0.1f*(a.z-r.z); d.w = 0.1f*(a.w-r.w);
      *(float4*)(&dl[tt*S + sq*4]) = d;
    }
    __syncthreads();
    for (int tt=0; tt<SUB; ++tt){
      float wv[8];
      #pragma unroll
      for (int i=0;i<8;i++) wv[i] = wl[(tm+16*i)*66 + tt];
      if constexpr (S==128){
        float4 d0 = *(const float4*)(&dl[tt*128 + ts*4]);
        float4 d1 = *(const float4*)(&dl[tt*128 + 64 + ts*4]);
        #pragma unroll
        for (int i=0;i<8;i++){
          acc[i][0] += wv[i]*d0.x; acc[i][1] += wv[i]*d0.y;
          acc[i][2] += wv[i]*d0.z; acc[i][3] += wv[i]*d0.w;
          acc[i][4] += wv[i]*d1.x; acc[i][5] += wv[i]*d1.y;
          acc[i][6] += wv[i]*d1.z; acc[i][7] += wv[i]*d1.w;
        }
      } else {
        float dv = dl[tt*16 + ts];
        #pragma unroll
        for (int i=0;i<8;i++) acc[i][0] += wv[i]*dv;
      }
    }
    __syncthreads();
  }
  if constexpr (S==128){
    #pragma unroll
    for (int i=0;i<8;i++){
      #pragma unroll
      for (int j=0;j<4;j++){
        atomicAdd(&delta[(tm+16*i)*128 + ts*4 + j], acc[i][j]);
        atomicAdd(&delta[(tm+16*i)*128 + 64 + ts*4 + j], acc[i][4+j]);
      }
    }
  } else {
    #pragma unroll
    for (int i=0;i<8;i++)
      atomicAdd(&delta[(tm+16*i)*16 + ts], acc[i][0]);
  }
}

// ---------------- BN finalize ----------------
__global__ void k_bnfin(const double* __restrict__ stats, const float* __restrict__ g,
                        const float* __restrict__ b, float* __restrict__ sc,
                        float* __restrict__ sh, int C, double invT){
  int c = threadIdx.x; if (c >= C) return;
  double mean = stats[c]*invT;
  double var = stats[C+c]*invT - mean*mean;
  if (var < 0.0) var = 0.0;
  double s = (double)g[c] / sqrt(var + 1e-5);
  sc[c] = (float)s; sh[c] = (float)((double)b[c] - mean*s);
}

// ---------------- deconv 4x4 stride2 pad1, CIN=128 NHWC(+bn) -> CO=3 NHWC, silu ----------------
__global__ __launch_bounds__(256)
void k_deconv(const float* __restrict__ in, const float* __restrict__ wd,
              const float* __restrict__ bias, float* __restrict__ out,
              const float* __restrict__ sc, const float* __restrict__ sh){
  __shared__ float lds[2*130*128];
  __shared__ float scl[128], shl[128];
  int t = threadIdx.x;
  int oy = blockIdx.x & 255; int b = blockIdx.x >> 8;
  if (t < 128){ scl[t]=sc[t]; shl[t]=sh[t]; }
  __syncthreads();
  int p = (oy+1)&1;
  int iy_hi = (oy+1-p)>>1;
  for (int r=0;r<2;r++){
    int iy = iy_hi - 1 + r;
    bool valid = (unsigned)iy < 128u;
    const float* rp = in + ((size_t)b*128 + iy)*128*128;
    for (int i=t; i<130*32; i+=256){
      int col=i/32, cq=i%32;
      int ix = col-1;
      float4 v = make_float4(0.f,0.f,0.f,0.f);
      if (valid && (unsigned)ix<128u){
        v = *(const float4*)(rp + (size_t)ix*128 + cq*4);
        v.x = v.x*scl[cq*4+0]+shl[cq*4+0];
        v.y = v.y*scl[cq*4+1]+shl[cq*4+1];
        v.z = v.z*scl[cq*4+2]+shl[cq*4+2];
        v.w = v.w*scl[cq*4+3]+shl[cq*4+3];
      }
      *(float4*)(&lds[(r*130+col)*128 + cq*4]) = v;
    }
  }
  __syncthreads();
  int ox = t;
  int px_ = (ox+1)&1;
  int ix_hi = (ox+1-px_)>>1;
  float acc0=bias[0], acc1=bias[1], acc2=bias[2];
  for (int ry=0; ry<2; ++ry){
    for (int cx=0; cx<2; ++cx){
      int kx = px_ + 2*(1-cx);
      int ix = ix_hi - (1-cx);
      int lcol = ix + 1;
      int ky = p + 2*(1-ry);
      int tap = ky*4 + kx;
      const float* lp = &lds[(ry*130 + lcol)*128];
      const float* wp = wd + (size_t)tap*128*3;
      for (int cq=0; cq<32; ++cq){
        float4 a = *(const float4*)(lp + cq*4);
        float4 w0 = *(const float4*)(wp + cq*12);
        float4 w1 = *(const float4*)(wp + cq*12+4);
        float4 w2 = *(const float4*)(wp + cq*12+8);
        acc0 += a.x*w0.x + a.y*w0.w + a.z*w1.z + a.w*w2.y;
        acc1 += a.x*w0.y + a.y*w1.x + a.z*w1.w + a.w*w2.z;
        acc2 += a.x*w0.z + a.y*w1.y + a.z*w2.x + a.w*w2.w;
      }
    }
  }
  float* op = out + (((size_t)b*256 + oy)*256 + ox)*3;
  op[0]=silu_f(acc0); op[1]=silu_f(acc1); op[2]=silu_f(acc2);
}

// ---------------- final conv 3x3, 3->3, NHWC in -> NCHW out, silu ----------------
__global__ __launch_bounds__(256)
void k_conv33(const float* __restrict__ in, const float* __restrict__ wt,
              const float* __restrict__ bias, float* __restrict__ out){
  int pidx = blockIdx.x*256 + threadIdx.x;
  int b = pidx >> 16; int rem = pidx & 65535;
  int y = rem >> 8, x = rem & 255;
  float a0=bias[0], a1=bias[1], a2=bias[2];
  for (int dy=0;dy<3;dy++){
    int yy=y+dy-1; if((unsigned)yy>=256u) continue;
    for (int dx=0;dx<3;dx++){
      int xx2=x+dx-1; if((unsigned)xx2>=256u) continue;
      const float* ip = in + (((size_t)b*256+yy)*256+xx2)*3;
      #pragma unroll
      for (int ci=0;ci<3;ci++){
        float v = ip[ci];
        const float* wp = wt + (ci*9 + dy*3 + dx)*3;
        a0 += v*wp[0]; a1 += v*wp[1]; a2 += v*wp[2];
      }
    }
  }
  size_t o = (size_t)b*3*65536 + (size_t)y*256 + x;
  out[o]         = silu_f(a0);
  out[o+65536]   = silu_f(a1);
  out[o+2*65536] = silu_f(a2);
}

// ================= host side =================
extern "C" void kernel_launch(void* const* d_in, const int* in_sizes, int n_in,
                              void* d_out, int out_size, void* d_ws, size_t ws_size,
                              hipStream_t stream) {
  const float* x       = (const float*)d_in[0];
  const float* e0n_w1  = (const float*)d_in[1];
  const float* e0n_b1  = (const float*)d_in[2];
  const float* e0n_w2  = (const float*)d_in[3];
  const float* e0n_b2  = (const float*)d_in[4];
  const float* e0s_w1  = (const float*)d_in[5];
  const float* e0s_b1  = (const float*)d_in[6];
  const float* e0s_w2  = (const float*)d_in[7];
  const float* e0s_b2  = (const float*)d_in[8];
  const float* bnn_w1  = (const float*)d_in[9];
  const float* bnn_b1  = (const float*)d_in[10];
  const float* bnn_w2  = (const float*)d_in[11];
  const float* bnn_b2  = (const float*)d_in[12];
  const float* bns_w1  = (const float*)d_in[13];
  const float* bns_b1  = (const float*)d_in[14];
  const float* bns_w2  = (const float*)d_in[15];
  const float* bns_b2  = (const float*)d_in[16];
  const float* d0_wt   = (const float*)d_in[17];
  const float* d0_bt   = (const float*)d_in[18];
  const float* d0_wc   = (const float*)d_in[19];
  const float* d0_bc   = (const float*)d_in[20];
  const float* g0      = (const float*)d_in[21];
  const float* be0     = (const float*)d_in[22];
  const float* gb      = (const float*)d_in[23];
  const float* bb      = (const float*)d_in[24];
  const float* gd      = (const float*)d_in[25];
  const float* bd      = (const float*)d_in[26];
  const float* c0_zhat = (const float*)d_in[27];
  const float* c0_That = (const float*)d_in[28];
  const float* cb_zhat = (const float*)d_in[29];
  const float* cb_That = (const float*)d_in[30];

  char* wsb = (char*)d_ws;
  const size_t SLOT = 33554432ull;
  const size_t R1 = 4*SLOT;
  const size_t R2 = R1 + 16777216ull;
  const size_t R3 = R2 + 4194304ull;
  const size_t R4 = R3 + 33554432ull;
  const size_t WB = R4 + 81920ull;
  const size_t NEED = WB + 1967104ull;
  if (ws_size < NEED) return;

  float* t1    = (float*)(wsb + 0);
  float* w0T   = (float*)(wsb + 0);
  float* u2    = (float*)(wsb + 0);
  float* xt3   = (float*)(wsb + 0);
  float* read0 = (float*)(wsb + SLOT);
  float* w2T   = (float*)(wsb + SLOT);
  float* xt1   = (float*)(wsb + 2*SLOT);
  float* wbT   = (float*)(wsb + 2*SLOT);
  float* u1    = (float*)(wsb + 3*SLOT);
  float* t0    = (float*)(wsb + R1);
  float* bnnb  = (float*)(wsb + R1);
  float* bnsb  = (float*)(wsb + R1 + 4194304ull);
  float* readb = (float*)(wsb + R1 + 8388608ull);
  float* xt2   = (float*)(wsb + R1 + 12582912ull);
  float* e0n   = (float*)(wsb + R2);
  float* y1    = (float*)(wsb + R2);
  float* e0s   = (float*)(wsb + R3);
  float* delta0 = (float*)(wsb + R4);
  float* deltab = (float*)(wsb + R4 + 65536ull);
  double* stats0 = (double*)(wsb + R4 + 73728ull);
  double* statsb = (double*)(wsb + R4 + 75776ull);
  double* statsd = (double*)(wsb + R4 + 76288ull);
  float* sc0 = (float*)(wsb + R4 + 78336ull);
  float* sh0 = (float*)(wsb + R4 + 78848ull);
  float* scb = (float*)(wsb + R4 + 79360ull);
  float* shb = (float*)(wsb + R4 + 79872ull);
  float* scd = (float*)(wsb + R4 + 80384ull);
  float* shd = (float*)(wsb + R4 + 80896ull);
  float* wt_e0n1 = (float*)(wsb + WB);
  float* wt_e0n2 = (float*)(wsb + WB + 2048ull);
  float* wt_e0s1 = (float*)(wsb + WB + 11264ull);
  float* wt_e0s2 = (float*)(wsb + WB + 25088ull);
  float* wt_bnn1 = (float*)(wsb + WB + 614912ull);
  float* wt_bnn2 = (float*)(wsb + WB + 1204736ull);
  float* wt_bns1 = (float*)(wsb + WB + 1278464ull);
  float* wt_bns2 = (float*)(wsb + WB + 1868288ull);
  float* wt_d0c  = (float*)(wsb + WB + 1942016ull);
  float* wd_dec  = (float*)(wsb + WB + 1942528ull);

  const int T = 65536;
  const double invT = 1.0/65536.0;

  k_zero<<<77, 256, 0, stream>>>((float*)(wsb + R4), 19584);

  XArgs xa;
  xa.j[0] = { e0n_w1, wt_e0n1, 3, 16, 432, 0 };
  xa.j[1] = { e0n_w2, wt_e0n2, 16, 16, 2304, 0 };
  xa.j[2] = { e0s_w1, wt_e0s1, 3, 128, 3456, 0 };
  xa.j[3] = { e0s_w2, wt_e0s2, 128, 128, 147456, 1 };
  xa.j[4] = { bnn_w1, wt_bnn1, 128, 128, 147456, 1 };
  xa.j[5] = { bnn_w2, wt_bnn2, 128, 16, 18432, 1 };
  xa.j[6] = { bns_w1, wt_bns1, 128, 128, 147456, 1 };
  xa.j[7] = { bns_w2, wt_bns2, 128, 16, 18432, 1 };
  xa.j[8] = { d0_wc,  wt_d0c,  3, 3, 81, 0 };
  xa.j[9] = { d0_wt,  wd_dec,  128, 3, 6144, 2 };
  k_xform<<<dim3(576,10), 256, 0, stream>>>(xa);

  // encoder stems
  k_conv_cin3<16><<<4096, 256, 0, stream>>>(x, wt_e0n1, e0n_b1, t0);
  k_conv_cin3<128><<<32768, 256, 0, stream>>>(x, wt_e0s1, e0s_b1, t1);
  k_rowconv<16,16,2,128><<<512, 256, 0, stream>>>(t0, wt_e0n2, e0n_b2, e0n, 256, 256);
  // e0s conv2: stride2, tile 2x16: grid = (128/16)*(128/2)*4 = 2048
  k_conv3<2,2,16,128,8><<<2048, 256, 0, stream>>>(t1, wt_e0s2, e0s_b2, e0s, nullptr, nullptr, 256, 256);

  // memcell 0 write
  k_weights<<<256, 256, 0, stream>>>(e0n, c0_zhat, w0T, nullptr, nullptr, T);
  k_gemm128<false,false,false,false><<<1024, 256, 0, stream>>>(w0T, c0_That, nullptr, nullptr, read0, nullptr, T);
  k_delta<128><<<512, 256, 0, stream>>>(w0T, e0s, read0, delta0, T, 128);
  k_gemm128<true,true,true,false><<<1024, 256, 0, stream>>>(w0T, delta0, nullptr, read0, xt1, stats0, T);
  k_bnfin<<<1, 128, 0, stream>>>(stats0, g0, be0, sc0, sh0, 128, invT);

  // bottleneck branches (bn folded into staging): tile 4x32, grid = 4*32*4 = 512
  k_conv3<1,4,32,128,8><<<512, 256, 0, stream>>>(xt1, wt_bnn1, bnn_b1, u1, sc0, sh0, 128, 128);
  k_conv3<1,4,32,16,8><<<512, 256, 0, stream>>>(u1, wt_bnn2, bnn_b2, bnnb, nullptr, nullptr, 128, 128);
  k_conv3<1,4,32,128,8><<<512, 256, 0, stream>>>(xt1, wt_bns1, bns_b1, u2, sc0, sh0, 128, 128);
  k_conv3<1,4,32,16,8><<<512, 256, 0, stream>>>(u2, wt_bns2, bns_b2, bnsb, nullptr, nullptr, 128, 128);

  // memcell b write
  k_weights<<<256, 256, 0, stream>>>(bnnb, cb_zhat, wbT, nullptr, nullptr, T);
  k_gemm16<false,false,false><<<512, 256, 0, stream>>>(wbT, cb_That, nullptr, readb, nullptr, T);
  k_delta<16><<<512, 256, 0, stream>>>(wbT, bnsb, readb, deltab, T, 128);
  k_gemm16<true,true,true><<<512, 256, 0, stream>>>(wbT, deltab, readb, xt2, statsb, T);
  k_bnfin<<<1, 64, 0, stream>>>(statsb, gb, bb, scb, shb, 16, invT);

  // decoder recall-read against cell 0
  k_weights<<<256, 256, 0, stream>>>(xt2, c0_zhat, w2T, scb, shb, T);
  k_gemm128<false,true,true,true><<<1024, 256, 0, stream>>>(w2T, c0_That, delta0, nullptr, xt3, statsd, T);
  k_bnfin<<<1, 128, 0, stream>>>(statsd, gd, bd, scd, shd, 128, invT);

  // deconv + final conv
  k_deconv<<<1024, 256, 0, stream>>>(xt3, wd_dec, d0_bt, y1, scd, shd);
  k_conv33<<<1024, 256, 0, stream>>>(y1, wt_d0c, d0_bc, (float*)d_out);
}

// Round 8
// 1805.727 us; speedup vs baseline: 1.8993x; 1.1116x over previous
//
#include <hip/hip_runtime.h>
#include <math.h>

#define DEVI __device__ __forceinline__

DEVI float silu_f(float x){ return x / (1.0f + __expf(-x)); }

// ---------------- utility: zero a float region ----------------
__global__ void k_zero(float* p, int n){
  int i = blockIdx.x*256 + threadIdx.x;
  if (i < n) p[i] = 0.f;
}

// ---------------- weight transforms ----------------
// mode 0: OIHW [CO][CI][3][3] -> K-major [ci*9+tap][CO]
// mode 1: OIHW -> tap-major [tap][ci][CO]
// mode 2: deconv [CI=128][CO=3][4][4] -> [tap][ci][co]
struct XJob { const float* src; float* dst; int ci, co, n, mode; };
struct XArgs { XJob j[10]; };

__global__ void k_xform(XArgs a){
  XJob jb = a.j[blockIdx.y];
  int e = blockIdx.x*256 + threadIdx.x;
  if (e >= jb.n) return;
  if (jb.mode == 0){
    int co = e % jb.co; int k = e / jb.co; int ci = k/9; int jj = k - ci*9;
    jb.dst[e] = jb.src[(co*jb.ci + ci)*9 + jj];
  } else if (jb.mode == 1){
    int co = e % jb.co; int r = e / jb.co; int ci = r % jb.ci; int tap = r / jb.ci;
    jb.dst[e] = jb.src[(co*jb.ci + ci)*9 + tap];
  } else {
    int co = e % 3; int r = e/3; int ci = r & 127; int tap = r >> 7;
    int ky = tap >> 2, kx = tap & 3;
    jb.dst[e] = jb.src[((ci*3 + co)*4 + ky)*4 + kx];
  }
}

// ---------------- conv 3x3, CIN=3, NCHW input -> NHWC output, silu ----------------
template<int CO>
__global__ __launch_bounds__(256)
void k_conv_cin3(const float* __restrict__ x, const float* __restrict__ wt,
                 const float* __restrict__ bias, float* __restrict__ out){
  constexpr int CO4 = CO/4;
  constexpr int PPB = 256/CO4;
  int t = threadIdx.x;
  int co4 = t % CO4, pi = t / CO4;
  int p = blockIdx.x*PPB + pi;
  int b = p >> 16;
  int rem = p & 65535;
  int y = rem >> 8, xx = rem & 255;
  float4 acc = *(const float4*)(bias + co4*4);
  #pragma unroll
  for (int ci = 0; ci < 3; ++ci)
    for (int dy = 0; dy < 3; ++dy){
      int yy = y + dy - 1;
      if ((unsigned)yy >= 256u) continue;
      for (int dx = 0; dx < 3; ++dx){
        int xg = xx + dx - 1;
        if ((unsigned)xg >= 256u) continue;
        float v = x[(((size_t)b*3 + ci)*256 + yy)*256 + xg];
        int k = ci*9 + dy*3 + dx;
        float4 w = *(const float4*)(wt + (size_t)k*CO + co4*4);
        acc.x += v*w.x; acc.y += v*w.y; acc.z += v*w.z; acc.w += v*w.w;
      }
    }
  float4 o; o.x = silu_f(acc.x); o.y = silu_f(acc.y); o.z = silu_f(acc.z); o.w = silu_f(acc.w);
  *(float4*)(out + (size_t)p*CO + co4*4) = o;
}

// ---------------- CIN=128 3x3 conv, LDS-staged weights per (ck,dy,dx) ----------------
// weights tap-major [tap][ci][CO]; wl = 32 ci x CO (stride CO+4). 3 blocks/CU.
template<int STRIDE, int R, int C, int CO, int COPT>
__global__ __launch_bounds__(256, 3)
void k_conv3(const float* __restrict__ in, const float* __restrict__ wt,
             const float* __restrict__ bias, float* __restrict__ out,
             const float* __restrict__ sc, const float* __restrict__ sh,
             int H_in, int W_in){
  constexpr int IR = R*STRIDE + 2;
  constexpr int IC = C*STRIDE + 2;
  constexpr int COG = CO/COPT;
  constexpr int PG = 256/COG;
  constexpr int PX = (R*C)/PG;
  constexpr int NV = COPT/4;
  constexpr int CPAD = 36;
  constexpr int WSTR = CO + 4;
  __shared__ float xin[IR*IC*CPAD];
  __shared__ float wl[32*WSTR];
  __shared__ float scl[128], shl[128];
  int t = threadIdx.x;
  int cog = t / PG, pg = t % PG;
  const int HO = H_in/STRIDE, WO = W_in/STRIDE;
  const int SEGC = WO / C, NRB = HO / R;
  int bx = blockIdx.x;
  int seg = bx % SEGC; int rb = (bx/SEGC) % NRB; int b = bx/(SEGC*NRB);
  int ry0 = rb*R*STRIDE, cx0 = seg*C*STRIDE;
  bool hasS = (sc != nullptr);
  if (t < 128){ scl[t] = hasS ? sc[t] : 1.f; shl[t] = hasS ? sh[t] : 0.f; }
  float acc[PX][COPT];
  #pragma unroll
  for (int i=0;i<PX;i++)
    #pragma unroll
    for (int v=0;v<NV;v++){
      float4 bv = *(const float4*)(bias + cog*COPT + v*4);
      acc[i][v*4+0]=bv.x; acc[i][v*4+1]=bv.y; acc[i][v*4+2]=bv.z; acc[i][v*4+3]=bv.w;
    }
  int pbase[PX], prow[PX], pcol[PX];
  #pragma unroll
  for (int i=0;i<PX;i++){
    int p = pg + PG*i; int pr = p / C; int pc = p % C;
    prow[i] = pr; pcol[i] = pc;
    pbase[i] = (pr*STRIDE*IC + pc*STRIDE)*CPAD;
  }
  for (int ck=0; ck<4; ++ck){
    __syncthreads();   // prior ck's reads of xin/wl done
    // ---- stage input chunk (32 ci) ----
    for (int e=t; e<IR*IC*8; e+=256){
      int cq = e & 7; int rc = e >> 3; int ic = rc % IC; int ir = rc / IC;
      int gy = ry0 + ir - 1, gx = cx0 + ic - 1;
      float4 v = make_float4(0.f,0.f,0.f,0.f);
      if ((unsigned)gy < (unsigned)H_in && (unsigned)gx < (unsigned)W_in){
        int cb = ck*32 + cq*4;
        v = *(const float4*)(in + (((size_t)b*H_in + gy)*(size_t)W_in + gx)*128 + cb);
        v.x = v.x*scl[cb+0] + shl[cb+0];
        v.y = v.y*scl[cb+1] + shl[cb+1];
        v.z = v.z*scl[cb+2] + shl[cb+2];
        v.w = v.w*scl[cb+3] + shl[cb+3];
      }
      *(float4*)(&xin[rc*CPAD + cq*4]) = v;
    }
    for (int dy=0; dy<3; ++dy){
      for (int dx=0; dx<3; ++dx){
        if (dy || dx) __syncthreads();  // prior tap's wl reads done
        // ---- stage weights for (ck,dy,dx): 32 ci x CO ----
        for (int e=t; e<32*(CO/4); e+=256){
          int co4 = e % (CO/4); int ci = e / (CO/4);
          float4 wv = *(const float4*)(wt + ((size_t)((dy*3+dx)*128 + ck*32 + ci))*CO + co4*4);
          *(float4*)(&wl[ci*WSTR + co4*4]) = wv;
        }
        __syncthreads();  // staging visible (xin too on first tap)
        // ---- hot loop: pure LDS ----
        #pragma unroll 2
        for (int ciq=0; ciq<8; ++ciq){
          float4 a4[PX];
          #pragma unroll
          for (int i=0;i<PX;i++)
            a4[i] = *(const float4*)(&xin[pbase[i] + (dy*IC + dx)*CPAD + ciq*4]);
          #pragma unroll
          for (int c=0;c<4;c++){
            const float* wrow = &wl[(ciq*4 + c)*WSTR + cog*COPT];
            float4 w0 = *(const float4*)(wrow);
            float4 w1;
            if (NV==2) w1 = *(const float4*)(wrow + 4);
            #pragma unroll
            for (int i=0;i<PX;i++){
              float av = (c==0)?a4[i].x:(c==1)?a4[i].y:(c==2)?a4[i].z:a4[i].w;
              acc[i][0] += av*w0.x; acc[i][1] += av*w0.y; acc[i][2] += av*w0.z; acc[i][3] += av*w0.w;
              if (NV==2){
                acc[i][4] += av*w1.x; acc[i][5] += av*w1.y; acc[i][6] += av*w1.z; acc[i][7] += av*w1.w;
              }
            }
          }
        }
      }
    }
  }
  // ---- epilogue ----
  #pragma unroll
  for (int i=0;i<PX;i++){
    int orow = rb*R + prow[i], ocol = seg*C + pcol[i];
    float* op = out + (((size_t)b*HO + orow)*WO + ocol)*CO + cog*COPT;
    #pragma unroll
    for (int v=0;v<NV;v++){
      float4 o;
      o.x = silu_f(acc[i][v*4+0]); o.y = silu_f(acc[i][v*4+1]);
      o.z = silu_f(acc[i][v*4+2]); o.w = silu_f(acc[i][v*4+3]);
      *(float4*)(op + v*4) = o;
    }
  }
}

// ---------------- CIN=16 3x3 stride2 conv (e0n stem), LDS stride 20 ----------------
template<int CIN, int CO, int STRIDE, int PXB>
__global__ __launch_bounds__(256)
void k_rowconv(const float* __restrict__ in, const float* __restrict__ wt,
               const float* __restrict__ bias, float* __restrict__ out,
               int H_in, int W_in){
  constexpr int WT = PXB*STRIDE + 2;
  constexpr int CO8 = CO/8;
  constexpr int PG = 256/CO8;
  constexpr int PPT = PXB/PG;
  constexpr int SEGS = 128/PXB;
  constexpr int LSTR = CIN + 4;
  __shared__ float lds[WT*LSTR];
  int t = threadIdx.x;
  int co8 = t % CO8, pg = t / CO8;
  int blk = blockIdx.x;
  int seg = blk % SEGS; int oy = (blk/SEGS) & 127; int b = blk/(SEGS*128);
  int x0 = seg*PXB;
  float acc[PPT][8];
  {
    float4 b0 = *(const float4*)(bias + co8*8);
    float4 b1 = *(const float4*)(bias + co8*8 + 4);
    #pragma unroll
    for (int i=0;i<PPT;i++){
      acc[i][0]=b0.x; acc[i][1]=b0.y; acc[i][2]=b0.z; acc[i][3]=b0.w;
      acc[i][4]=b1.x; acc[i][5]=b1.y; acc[i][6]=b1.z; acc[i][7]=b1.w;
    }
  }
  const int gx0 = x0*STRIDE - 1;
  for (int dy=0; dy<3; ++dy){
    int iy = oy*STRIDE + dy - 1;
    if ((unsigned)iy < (unsigned)H_in){
      const float* rowp = in + ((size_t)b*H_in + iy)*(size_t)W_in*CIN;
      for (int i = t; i < WT*(CIN/4); i += 256){
        int col = i / (CIN/4); int cq = i % (CIN/4);
        int gx = gx0 + col;
        float4 v = make_float4(0.f,0.f,0.f,0.f);
        if ((unsigned)gx < (unsigned)W_in)
          v = *(const float4*)(rowp + (size_t)gx*CIN + cq*4);
        *(float4*)(&lds[col*LSTR + cq*4]) = v;
      }
      __syncthreads();
      for (int dx=0; dx<3; ++dx){
        for (int cq=0; cq<CIN/4; ++cq){
          float4 a4[PPT];
          #pragma unroll
          for (int i=0;i<PPT;i++){
            int lx = (pg*PPT + i)*STRIDE + dx;
            a4[i] = *(const float4*)(&lds[lx*LSTR + cq*4]);
          }
          const float* wk = wt + ((size_t)(cq*4)*9 + dy*3 + dx)*CO + co8*8;
          #pragma unroll
          for (int cc=0; cc<4; ++cc){
            float4 w0 = *(const float4*)(wk + (size_t)cc*9*CO);
            float4 w1 = *(const float4*)(wk + (size_t)cc*9*CO + 4);
            #pragma unroll
            for (int i=0;i<PPT;i++){
              float av = (cc==0) ? a4[i].x : (cc==1) ? a4[i].y : (cc==2) ? a4[i].z : a4[i].w;
              acc[i][0] += av*w0.x; acc[i][1] += av*w0.y; acc[i][2] += av*w0.z; acc[i][3] += av*w0.w;
              acc[i][4] += av*w1.x; acc[i][5] += av*w1.y; acc[i][6] += av*w1.z; acc[i][7] += av*w1.w;
            }
          }
        }
      }
      __syncthreads();
    }
  }
  #pragma unroll
  for (int i=0;i<PPT;i++){
    int px = x0 + pg*PPT + i;
    float4 o0, o1;
    o0.x = silu_f(acc[i][0]); o0.y = silu_f(acc[i][1]); o0.z = silu_f(acc[i][2]); o0.w = silu_f(acc[i][3]);
    o1.x = silu_f(acc[i][4]); o1.y = silu_f(acc[i][5]); o1.z = silu_f(acc[i][6]); o1.w = silu_f(acc[i][7]);
    float* op = out + (((size_t)b*128 + oy)*128 + px)*CO + co8*8;
    *(float4*)op = o0; *(float4*)(op+4) = o1;
  }
}

// ---------------- memcell weights ----------------
__global__ __launch_bounds__(256)
void k_weights(const float* __restrict__ z, const float* __restrict__ zhat,
               float* __restrict__ wT, const float* __restrict__ sc,
               const float* __restrict__ sh, int T){
  __shared__ float zl[128*16];
  __shared__ float zn[128];
  __shared__ float scl[16], shl[16];
  int t = threadIdx.x;
  if (t < 128){
    float s2 = 0.f;
    #pragma unroll
    for (int j=0;j<16;j++){ float v = zhat[t*16+j]; zl[t*16+j] = v; s2 += v*v; }
    zn[t] = s2;
  }
  if (t < 16){ scl[t] = sc ? sc[t] : 1.f; shl[t] = sh ? sh[t] : 0.f; }
  __syncthreads();
  size_t tok = (size_t)blockIdx.x*256 + t;
  float zr[16];
  #pragma unroll
  for (int q=0;q<4;q++){
    float4 v = *(const float4*)(z + tok*16 + q*4);
    zr[q*4+0] = v.x*scl[q*4+0]+shl[q*4+0];
    zr[q*4+1] = v.y*scl[q*4+1]+shl[q*4+1];
    zr[q*4+2] = v.z*scl[q*4+2]+shl[q*4+2];
    zr[q*4+3] = v.w*scl[q*4+3]+shl[q*4+3];
  }
  float mx = -1e30f;
  for (int m=0;m<128;m++){
    float d=0.f;
    #pragma unroll
    for (int j=0;j<16;j++) d += zr[j]*zl[m*16+j];
    float s = 5.0f*(2.f*d - zn[m]);
    mx = fmaxf(mx, s);
  }
  float sum=0.f;
  for (int m=0;m<128;m++){
    float d=0.f;
    #pragma unroll
    for (int j=0;j<16;j++) d += zr[j]*zl[m*16+j];
    sum += __expf(5.0f*(2.f*d - zn[m]) - mx);
  }
  float inv = 1.f/sum;
  for (int m=0;m<128;m++){
    float d=0.f;
    #pragma unroll
    for (int j=0;j<16;j++) d += zr[j]*zl[m*16+j];
    wT[(size_t)m*T + tok] = __expf(5.0f*(2.f*d - zn[m]) - mx)*inv;
  }
}

// ---------------- S=128 GEMM ----------------
template<bool ADD, bool DOTANH, bool STATS, bool MAT2>
__global__ __launch_bounds__(256)
void k_gemm128(const float* __restrict__ wT, const float* __restrict__ mat1,
               const float* __restrict__ mat2, const float* __restrict__ addsrc,
               float* __restrict__ dst, double* __restrict__ stats, int T){
  __shared__ float4 ml4[128*32];
  __shared__ float ssum[128], ssq[128];
  int t = threadIdx.x;
  if (STATS && t < 128){ ssum[t]=0.f; ssq[t]=0.f; }
  for (int i=t; i < 128*32; i += 256){
    float4 v = ((const float4*)mat1)[i];
    if (MAT2){ float4 u = ((const float4*)mat2)[i]; v.x+=u.x; v.y+=u.y; v.z+=u.z; v.w+=u.w; }
    ml4[i] = v;
  }
  __syncthreads();
  int s16 = t & 15, tg = t >> 4;
  size_t tb = (size_t)blockIdx.x*64;
  float accA[4][4], accB[4][4];
  #pragma unroll
  for (int i=0;i<4;i++) for (int j=0;j<4;j++){ accA[i][j]=0.f; accB[i][j]=0.f; }
  const float* wp = wT + tb + tg*4;
  #pragma unroll 4
  for (int m=0;m<128;m++){
    float4 wv = *(const float4*)(wp + (size_t)m*T);
    float4 c0 = ml4[m*32 + s16];
    float4 c1 = ml4[m*32 + 16 + s16];
    float w[4] = {wv.x,wv.y,wv.z,wv.w};
    #pragma unroll
    for (int i=0;i<4;i++){
      accA[i][0] += w[i]*c0.x; accA[i][1] += w[i]*c0.y; accA[i][2] += w[i]*c0.z; accA[i][3] += w[i]*c0.w;
      accB[i][0] += w[i]*c1.x; accB[i][1] += w[i]*c1.y; accB[i][2] += w[i]*c1.z; accB[i][3] += w[i]*c1.w;
    }
  }
  int colA = s16*4, colB = 64 + s16*4;
  float lsA[4], lqA[4], lsB[4], lqB[4];
  #pragma unroll
  for (int j=0;j<4;j++){ lsA[j]=0.f; lqA[j]=0.f; lsB[j]=0.f; lqB[j]=0.f; }
  #pragma unroll
  for (int i=0;i<4;i++){
    size_t tok = tb + tg*4 + i;
    float oA[4], oB[4];
    #pragma unroll
    for (int j=0;j<4;j++){ oA[j]=accA[i][j]; oB[j]=accB[i][j]; }
    if (ADD){
      float4 a0 = *(const float4*)(addsrc + tok*128 + colA);
      float4 a1 = *(const float4*)(addsrc + tok*128 + colB);
      oA[0]+=a0.x; oA[1]+=a0.y; oA[2]+=a0.z; oA[3]+=a0.w;
      oB[0]+=a1.x; oB[1]+=a1.y; oB[2]+=a1.z; oB[3]+=a1.w;
    }
    if (DOTANH){
      #pragma unroll
      for (int j=0;j<4;j++){ oA[j]=tanhf(oA[j]); oB[j]=tanhf(oB[j]); }
    }
    float4 r0 = {oA[0],oA[1],oA[2],oA[3]}, r1 = {oB[0],oB[1],oB[2],oB[3]};
    *(float4*)(dst + tok*128 + colA) = r0;
    *(float4*)(dst + tok*128 + colB) = r1;
    if (STATS){
      #pragma unroll
      for (int j=0;j<4;j++){
        lsA[j]+=oA[j]; lqA[j]+=oA[j]*oA[j];
        lsB[j]+=oB[j]; lqB[j]+=oB[j]*oB[j];
      }
    }
  }
  if (STATS){
    #pragma unroll
    for (int j=0;j<4;j++){
      atomicAdd(&ssum[colA+j], lsA[j]); atomicAdd(&ssq[colA+j], lqA[j]);
      atomicAdd(&ssum[colB+j], lsB[j]); atomicAdd(&ssq[colB+j], lqB[j]);
    }
    __syncthreads();
    if (t < 128){
      atomicAdd(&stats[t], (double)ssum[t]);
      atomicAdd(&stats[128+t], (double)ssq[t]);
    }
  }
}

// ---------------- S=16 GEMM ----------------
template<bool ADD, bool DOTANH, bool STATS>
__global__ __launch_bounds__(256)
void k_gemm16(const float* __restrict__ wT, const float* __restrict__ mat1,
              const float* __restrict__ addsrc, float* __restrict__ dst,
              double* __restrict__ stats, int T){
  __shared__ float ml[128*16];
  __shared__ float ssum[16], ssq[16];
  int t = threadIdx.x;
  if (STATS && t < 16){ ssum[t]=0.f; ssq[t]=0.f; }
  for (int i=t; i < 128*4; i += 256)
    ((float4*)ml)[i] = ((const float4*)mat1)[i];
  __syncthreads();
  size_t tb = (size_t)blockIdx.x*128;
  int s8 = t & 1, tg = t >> 1;
  float acc[8];
  #pragma unroll
  for (int j=0;j<8;j++) acc[j]=0.f;
  size_t tok = tb + tg;
  const float* wp = wT + tok;
  #pragma unroll 4
  for (int m=0;m<128;m++){
    float wv = wp[(size_t)m*T];
    float4 c0 = *(const float4*)(&ml[m*16 + s8*8]);
    float4 c1 = *(const float4*)(&ml[m*16 + s8*8 + 4]);
    acc[0]+=wv*c0.x; acc[1]+=wv*c0.y; acc[2]+=wv*c0.z; acc[3]+=wv*c0.w;
    acc[4]+=wv*c1.x; acc[5]+=wv*c1.y; acc[6]+=wv*c1.z; acc[7]+=wv*c1.w;
  }
  float o[8];
  #pragma unroll
  for (int j=0;j<8;j++) o[j]=acc[j];
  if (ADD){
    float4 a0 = *(const float4*)(addsrc + tok*16 + s8*8);
    float4 a1 = *(const float4*)(addsrc + tok*16 + s8*8+4);
    o[0]+=a0.x; o[1]+=a0.y; o[2]+=a0.z; o[3]+=a0.w;
    o[4]+=a1.x; o[5]+=a1.y; o[6]+=a1.z; o[7]+=a1.w;
  }
  if (DOTANH){
    #pragma unroll
    for (int j=0;j<8;j++) o[j]=tanhf(o[j]);
  }
  float4 r0 = {o[0],o[1],o[2],o[3]}, r1 = {o[4],o[5],o[6],o[7]};
  *(float4*)(dst + tok*16 + s8*8) = r0;
  *(float4*)(dst + tok*16 + s8*8 + 4) = r1;
  if (STATS){
    #pragma unroll
    for (int j=0;j<8;j++){ atomicAdd(&ssum[s8*8+j], o[j]); atomicAdd(&ssq[s8*8+j], o[j]*o[j]); }
    __syncthreads();
    if (t < 16){
      atomicAdd(&stats[t], (double)ssum[t]);
      atomicAdd(&stats[16+t], (double)ssq[t]);
    }
  }
}

// ---------------- delta[m][s] += sum_t wT[m][t] * ALPHA*(Tstar - read)[t][s] ----------------
template<int S>
__global__ __launch_bounds__(256)
void k_delta(const float* __restrict__ wT, const float* __restrict__ tstar,
             const float* __restrict__ rd, float* __restrict__ delta, int T, int KCH){
  constexpr int SUB = 64;
  constexpr int SJ = (S==128)?8:1;
  __shared__ float wl[128*66];
  __shared__ float dl[SUB*S];
  int t = threadIdx.x;
  int tm = t >> 4, ts = t & 15;
  size_t base = (size_t)blockIdx.x * KCH;
  float acc[8][SJ];
  #pragma unroll
  for (int i=0;i<8;i++) for (int j=0;j<SJ;j++) acc[i][j]=0.f;
  for (int c0=0; c0<KCH; c0+=SUB){
    for (int i=t; i<128*16; i+=256){
      int m = i >> 4; int tq = i & 15;
      float4 v = *(const float4*)(wT + (size_t)m*T + base + c0 + tq*4);
      float* wp = &wl[m*66 + tq*4];
      *(float2*)(wp)   = make_float2(v.x, v.y);
      *(float2*)(wp+2) = make_float2(v.z, v.w);
    }
    for (int i=t; i<SUB*S/4; i+=256){
      int tt = i/(S/4); int sq = i%(S/4);
      size_t tok = base + c0 + tt;
      float4 a = *(const float4*)(tstar + tok*S + sq*4);
      float4 r = *(const float4*)(rd + tok*S + sq*4);
      float4 d; d.x = 0.1f*(a.x-r.x); d.y = 0.1f*(a.y-r.y); d.z = 0.1f*(a.z-r.z); d.w = 0.1f*(a.w-r.w);
      *(float4*)(&dl[tt*S + sq*4]) = d;
    }
    __syncthreads();
    for (int tt=0; tt<SUB; ++tt){
      float wv[8];
      #pragma unroll
      for (int i=0;i<8;i++) wv[i] = wl[(tm+16*i)*66 + tt];
      if constexpr (S==128){
        float4 d0 = *(const float4*)(&dl[tt*128 + ts*4]);
        float4 d1 = *(const float4*)(&dl[tt*128 + 64 + ts*4]);
        #pragma unroll
        for (int i=0;i<8;i++){
          acc[i][0] += wv[i]*d0.x; acc[i][1] += wv[i]*d0.y;
          acc[i][2] += wv[i]*d0.z; acc[i][3] += wv[i]*d0.w;
          acc[i][4] += wv[i]*d1.x; acc[i][5] += wv[i]*d1.y;
          acc[i][6] += wv[i]*d1.z; acc[i][7] += wv[i]*d1.w;
        }
      } else {
        float dv = dl[tt*16 + ts];
        #pragma unroll
        for (int i=0;i<8;i++) acc[i][0] += wv[i]*dv;
      }
    }
    __syncthreads();
  }
  if constexpr (S==128){
    #pragma unroll
    for (int i=0;i<8;i++){
      #pragma unroll
      for (int j=0;j<4;j++){
        atomicAdd(&delta[(tm+16*i)*128 + ts*4 + j], acc[i][j]);
        atomicAdd(&delta[(tm+16*i)*128 + 64 + ts*4 + j], acc[i][4+j]);
      }
    }
  } else {
    #pragma unroll
    for (int i=0;i<8;i++)
      atomicAdd(&delta[(tm+16*i)*16 + ts], acc[i][0]);
  }
}

// ---------------- BN finalize ----------------
__global__ void k_bnfin(const double* __restrict__ stats, const float* __restrict__ g,
                        const float* __restrict__ b, float* __restrict__ sc,
                        float* __restrict__ sh, int C, double invT){
  int c = threadIdx.x; if (c >= C) return;
  double mean = stats[c]*invT;
  double var = stats[C+c]*invT - mean*mean;
  if (var < 0.0) var = 0.0;
  double s = (double)g[c] / sqrt(var + 1e-5);
  sc[c] = (float)s; sh[c] = (float)((double)b[c] - mean*s);
}

// ---------------- deconv 4x4 stride2 pad1: global-input, weights in LDS ----------------
__global__ __launch_bounds__(256)
void k_deconv(const float* __restrict__ in, const float* __restrict__ wd,
              const float* __restrict__ bias, float* __restrict__ out,
              const float* __restrict__ sc, const float* __restrict__ sh){
  __shared__ float wl[16*384];   // [tap][ci][co], 6144 floats
  __shared__ float scl[128], shl[128];
  int t = threadIdx.x;
  int oy = blockIdx.x & 255; int b = blockIdx.x >> 8;
  if (t < 128){ scl[t]=sc[t]; shl[t]=sh[t]; }
  for (int i=t; i<1536; i+=256)
    ((float4*)wl)[i] = ((const float4*)wd)[i];
  __syncthreads();
  int ox = t;
  int p = (oy+1)&1;
  int iy_hi = (oy+1-p)>>1;
  int px_ = (ox+1)&1;
  int ix_hi = (ox+1-px_)>>1;
  float acc0=bias[0], acc1=bias[1], acc2=bias[2];
  #pragma unroll
  for (int ry=0; ry<2; ++ry){
    int iy = iy_hi - 1 + ry;
    if ((unsigned)iy >= 128u) continue;
    int ky = p + 2*(1-ry);
    #pragma unroll
    for (int cx=0; cx<2; ++cx){
      int ix = ix_hi - (1-cx);
      if ((unsigned)ix >= 128u) continue;
      int kx = px_ + 2*(1-cx);
      int tap = ky*4 + kx;
      const float* ip = in + (((size_t)b*128 + iy)*128 + ix)*128;
      const float* wp = &wl[tap*384];
      for (int cq=0; cq<32; ++cq){
        float4 a = *(const float4*)(ip + cq*4);
        a.x = a.x*scl[cq*4+0]+shl[cq*4+0];
        a.y = a.y*scl[cq*4+1]+shl[cq*4+1];
        a.z = a.z*scl[cq*4+2]+shl[cq*4+2];
        a.w = a.w*scl[cq*4+3]+shl[cq*4+3];
        float4 w0 = *(const float4*)(wp + cq*12);
        float4 w1 = *(const float4*)(wp + cq*12+4);
        float4 w2 = *(const float4*)(wp + cq*12+8);
        acc0 += a.x*w0.x + a.y*w0.w + a.z*w1.z + a.w*w2.y;
        acc1 += a.x*w0.y + a.y*w1.x + a.z*w1.w + a.w*w2.z;
        acc2 += a.x*w0.z + a.y*w1.y + a.z*w2.x + a.w*w2.w;
      }
    }
  }
  float* op = out + (((size_t)b*256 + oy)*256 + ox)*3;
  op[0]=silu_f(acc0); op[1]=silu_f(acc1); op[2]=silu_f(acc2);
}

// ---------------- final conv 3x3, 3->3, NHWC in -> NCHW out, silu ----------------
__global__ __launch_bounds__(256)
void k_conv33(const float* __restrict__ in, const float* __restrict__ wt,
              const float* __restrict__ bias, float* __restrict__ out){
  int pidx = blockIdx.x*256 + threadIdx.x;
  int b = pidx >> 16; int rem = pidx & 65535;
  int y = rem >> 8, x = rem & 255;
  float a0=bias[0], a1=bias[1], a2=bias[2];
  for (int dy=0;dy<3;dy++){
    int yy=y+dy-1; if((unsigned)yy>=256u) continue;
    for (int dx=0;dx<3;dx++){
      int xx2=x+dx-1; if((unsigned)xx2>=256u) continue;
      const float* ip = in + (((size_t)b*256+yy)*256+xx2)*3;
      #pragma unroll
      for (int ci=0;ci<3;ci++){
        float v = ip[ci];
        const float* wp = wt + (ci*9 + dy*3 + dx)*3;
        a0 += v*wp[0]; a1 += v*wp[1]; a2 += v*wp[2];
      }
    }
  }
  size_t o = (size_t)b*3*65536 + (size_t)y*256 + x;
  out[o]         = silu_f(a0);
  out[o+65536]   = silu_f(a1);
  out[o+2*65536] = silu_f(a2);
}

// ================= host side =================
extern "C" void kernel_launch(void* const* d_in, const int* in_sizes, int n_in,
                              void* d_out, int out_size, void* d_ws, size_t ws_size,
                              hipStream_t stream) {
  const float* x       = (const float*)d_in[0];
  const float* e0n_w1  = (const float*)d_in[1];
  const float* e0n_b1  = (const float*)d_in[2];
  const float* e0n_w2  = (const float*)d_in[3];
  const float* e0n_b2  = (const float*)d_in[4];
  const float* e0s_w1  = (const float*)d_in[5];
  const float* e0s_b1  = (const float*)d_in[6];
  const float* e0s_w2  = (const float*)d_in[7];
  const float* e0s_b2  = (const float*)d_in[8];
  const float* bnn_w1  = (const float*)d_in[9];
  const float* bnn_b1  = (const float*)d_in[10];
  const float* bnn_w2  = (const float*)d_in[11];
  const float* bnn_b2  = (const float*)d_in[12];
  const float* bns_w1  = (const float*)d_in[13];
  const float* bns_b1  = (const float*)d_in[14];
  const float* bns_w2  = (const float*)d_in[15];
  const float* bns_b2  = (const float*)d_in[16];
  const float* d0_wt   = (const float*)d_in[17];
  const float* d0_bt   = (const float*)d_in[18];
  const float* d0_wc   = (const float*)d_in[19];
  const float* d0_bc   = (const float*)d_in[20];
  const float* g0      = (const float*)d_in[21];
  const float* be0     = (const float*)d_in[22];
  const float* gb      = (const float*)d_in[23];
  const float* bb      = (const float*)d_in[24];
  const float* gd      = (const float*)d_in[25];
  const float* bd      = (const float*)d_in[26];
  const float* c0_zhat = (const float*)d_in[27];
  const float* c0_That = (const float*)d_in[28];
  const float* cb_zhat = (const float*)d_in[29];
  const float* cb_That = (const float*)d_in[30];

  char* wsb = (char*)d_ws;
  const size_t SLOT = 33554432ull;
  const size_t R1 = 4*SLOT;
  const size_t R2 = R1 + 16777216ull;
  const size_t R3 = R2 + 4194304ull;
  const size_t R4 = R3 + 33554432ull;
  const size_t WB = R4 + 81920ull;
  const size_t NEED = WB + 1967104ull;
  if (ws_size < NEED) return;

  float* t1    = (float*)(wsb + 0);
  float* w0T   = (float*)(wsb + 0);
  float* u2    = (float*)(wsb + 0);
  float* xt3   = (float*)(wsb + 0);
  float* read0 = (float*)(wsb + SLOT);
  float* w2T   = (float*)(wsb + SLOT);
  float* xt1   = (float*)(wsb + 2*SLOT);
  float* wbT   = (float*)(wsb + 2*SLOT);
  float* u1    = (float*)(wsb + 3*SLOT);
  float* t0    = (float*)(wsb + R1);
  float* bnnb  = (float*)(wsb + R1);
  float* bnsb  = (float*)(wsb + R1 + 4194304ull);
  float* readb = (float*)(wsb + R1 + 8388608ull);
  float* xt2   = (float*)(wsb + R1 + 12582912ull);
  float* e0n   = (float*)(wsb + R2);
  float* y1    = (float*)(wsb + R2);
  float* e0s   = (float*)(wsb + R3);
  float* delta0 = (float*)(wsb + R4);
  float* deltab = (float*)(wsb + R4 + 65536ull);
  double* stats0 = (double*)(wsb + R4 + 73728ull);
  double* statsb = (double*)(wsb + R4 + 75776ull);
  double* statsd = (double*)(wsb + R4 + 76288ull);
  float* sc0 = (float*)(wsb + R4 + 78336ull);
  float* sh0 = (float*)(wsb + R4 + 78848ull);
  float* scb = (float*)(wsb + R4 + 79360ull);
  float* shb = (float*)(wsb + R4 + 79872ull);
  float* scd = (float*)(wsb + R4 + 80384ull);
  float* shd = (float*)(wsb + R4 + 80896ull);
  float* wt_e0n1 = (float*)(wsb + WB);
  float* wt_e0n2 = (float*)(wsb + WB + 2048ull);
  float* wt_e0s1 = (float*)(wsb + WB + 11264ull);
  float* wt_e0s2 = (float*)(wsb + WB + 25088ull);
  float* wt_bnn1 = (float*)(wsb + WB + 614912ull);
  float* wt_bnn2 = (float*)(wsb + WB + 1204736ull);
  float* wt_bns1 = (float*)(wsb + WB + 1278464ull);
  float* wt_bns2 = (float*)(wsb + WB + 1868288ull);
  float* wt_d0c  = (float*)(wsb + WB + 1942016ull);
  float* wd_dec  = (float*)(wsb + WB + 1942528ull);

  const int T = 65536;
  const double invT = 1.0/65536.0;

  k_zero<<<77, 256, 0, stream>>>((float*)(wsb + R4), 19584);

  XArgs xa;
  xa.j[0] = { e0n_w1, wt_e0n1, 3, 16, 432, 0 };
  xa.j[1] = { e0n_w2, wt_e0n2, 16, 16, 2304, 0 };
  xa.j[2] = { e0s_w1, wt_e0s1, 3, 128, 3456, 0 };
  xa.j[3] = { e0s_w2, wt_e0s2, 128, 128, 147456, 1 };
  xa.j[4] = { bnn_w1, wt_bnn1, 128, 128, 147456, 1 };
  xa.j[5] = { bnn_w2, wt_bnn2, 128, 16, 18432, 1 };
  xa.j[6] = { bns_w1, wt_bns1, 128, 128, 147456, 1 };
  xa.j[7] = { bns_w2, wt_bns2, 128, 16, 18432, 1 };
  xa.j[8] = { d0_wc,  wt_d0c,  3, 3, 81, 0 };
  xa.j[9] = { d0_wt,  wd_dec,  128, 3, 6144, 2 };
  k_xform<<<dim3(576,10), 256, 0, stream>>>(xa);

  // encoder stems
  k_conv_cin3<16><<<4096, 256, 0, stream>>>(x, wt_e0n1, e0n_b1, t0);
  k_conv_cin3<128><<<32768, 256, 0, stream>>>(x, wt_e0s1, e0s_b1, t1);
  k_rowconv<16,16,2,128><<<512, 256, 0, stream>>>(t0, wt_e0n2, e0n_b2, e0n, 256, 256);
  // e0s conv2: stride2, tile 2x16: grid = (128/16)*(128/2)*4 = 2048
  k_conv3<2,2,16,128,8><<<2048, 256, 0, stream>>>(t1, wt_e0s2, e0s_b2, e0s, nullptr, nullptr, 256, 256);

  // memcell 0 write
  k_weights<<<256, 256, 0, stream>>>(e0n, c0_zhat, w0T, nullptr, nullptr, T);
  k_gemm128<false,false,false,false><<<1024, 256, 0, stream>>>(w0T, c0_That, nullptr, nullptr, read0, nullptr, T);
  k_delta<128><<<512, 256, 0, stream>>>(w0T, e0s, read0, delta0, T, 128);
  k_gemm128<true,true,true,false><<<1024, 256, 0, stream>>>(w0T, delta0, nullptr, read0, xt1, stats0, T);
  k_bnfin<<<1, 128, 0, stream>>>(stats0, g0, be0, sc0, sh0, 128, invT);

  // bottleneck branches (bn folded into staging): tile 4x32, grid = 4*32*4 = 512
  k_conv3<1,4,32,128,8><<<512, 256, 0, stream>>>(xt1, wt_bnn1, bnn_b1, u1, sc0, sh0, 128, 128);
  k_conv3<1,4,32,16,8><<<512, 256, 0, stream>>>(u1, wt_bnn2, bnn_b2, bnnb, nullptr, nullptr, 128, 128);
  k_conv3<1,4,32,128,8><<<512, 256, 0, stream>>>(xt1, wt_bns1, bns_b1, u2, sc0, sh0, 128, 128);
  k_conv3<1,4,32,16,8><<<512, 256, 0, stream>>>(u2, wt_bns2, bns_b2, bnsb, nullptr, nullptr, 128, 128);

  // memcell b write
  k_weights<<<256, 256, 0, stream>>>(bnnb, cb_zhat, wbT, nullptr, nullptr, T);
  k_gemm16<false,false,false><<<512, 256, 0, stream>>>(wbT, cb_That, nullptr, readb, nullptr, T);
  k_delta<16><<<512, 256, 0, stream>>>(wbT, bnsb, readb, deltab, T, 128);
  k_gemm16<true,true,true><<<512, 256, 0, stream>>>(wbT, deltab, readb, xt2, statsb, T);
  k_bnfin<<<1, 64, 0, stream>>>(statsb, gb, bb, scb, shb, 16, invT);

  // decoder recall-read against cell 0
  k_weights<<<256, 256, 0, stream>>>(xt2, c0_zhat, w2T, scb, shb, T);
  k_gemm128<false,true,true,true><<<1024, 256, 0, stream>>>(w2T, c0_That, delta0, nullptr, xt3, statsd, T);
  k_bnfin<<<1, 128, 0, stream>>>(statsd, gd, bd, scd, shd, 128, invT);

  // deconv + final conv
  k_deconv<<<1024, 256, 0, stream>>>(xt3, wd_dec, d0_bt, y1, scd, shd);
  k_conv33<<<1024, 256, 0, stream>>>(y1, wt_d0c, d0_bc, (float*)d_out);
}

// Round 9
// 1360.721 us; speedup vs baseline: 2.5204x; 1.3270x over previous
//
#include <hip/hip_runtime.h>
#include <math.h>

#define DEVI __device__ __forceinline__

typedef __attribute__((ext_vector_type(8))) short short8_t;
typedef __attribute__((ext_vector_type(4))) float f32x4;

DEVI float silu_f(float x){ return x / (1.0f + __expf(-x)); }

DEVI unsigned bf16_rne(float x){
  unsigned u = __float_as_uint(x);
  return (u + 0x7FFFu + ((u>>16)&1u)) >> 16;
}

// ---------------- utility: zero a float region ----------------
__global__ void k_zero(float* p, int n){
  int i = blockIdx.x*256 + threadIdx.x;
  if (i < n) p[i] = 0.f;
}

// ---------------- small weight transforms (fp32 kernels) ----------------
// mode 0: OIHW [CO][CI][3][3] -> K-major [ci*9+tap][CO]
// mode 2: deconv [CI=128][CO=3][4][4] -> [tap][ci][co]
struct XJob { const float* src; float* dst; int ci, co, n, mode; };
struct XArgs { XJob j[5]; };

__global__ void k_xform(XArgs a){
  XJob jb = a.j[blockIdx.y];
  int e = blockIdx.x*256 + threadIdx.x;
  if (e >= jb.n) return;
  if (jb.mode == 0){
    int co = e % jb.co; int k = e / jb.co; int ci = k/9; int jj = k - ci*9;
    jb.dst[e] = jb.src[(co*jb.ci + ci)*9 + jj];
  } else {
    int co = e % 3; int r = e/3; int ci = r & 127; int tap = r >> 7;
    int ky = tap >> 2, kx = tap & 3;
    jb.dst[e] = jb.src[((ci*3 + co)*4 + ky)*4 + kx];
  }
}

// ---------------- bf16 hi/lo split weights, fragment-major ----------------
// dst layout: [chunk=ck*9+tap][co_rep][plane hi/lo][lane 0..63][elem 0..7]
// element (lane,i): ci = ck*32 + (lane>>4)*8 + i ; co = co_rep*16 + (lane&15)
struct WJob { const float* src; short* dst; int ncor; int n; };
struct WArgs { WJob j[5]; };

__global__ void k_wsplit(WArgs a){
  WJob jb = a.j[blockIdx.y];
  int e = blockIdx.x*256 + threadIdx.x;
  if (e >= jb.n) return;
  int i = e & 7;
  int l = (e>>3) & 63;
  int h = (e>>9) & 1;
  int rch = e >> 10;
  int r = rch % jb.ncor;
  int chunk = rch / jb.ncor;
  int tap = chunk % 9, ck = chunk / 9;
  int ci = ck*32 + ((l>>4)<<3) + i;
  int co = r*16 + (l&15);
  float wv = jb.src[((size_t)(co*128 + ci))*9 + tap];
  unsigned hi = bf16_rne(wv);
  unsigned o;
  if (h == 0) o = hi;
  else {
    float fh = __uint_as_float(hi<<16);
    o = bf16_rne(wv - fh);
  }
  jb.dst[e] = (short)o;
}

// ---------------- conv 3x3, CIN=3, NCHW input -> NHWC output, silu ----------------
template<int CO>
__global__ __launch_bounds__(256)
void k_conv_cin3(const float* __restrict__ x, const float* __restrict__ wt,
                 const float* __restrict__ bias, float* __restrict__ out){
  constexpr int CO4 = CO/4;
  constexpr int PPB = 256/CO4;
  int t = threadIdx.x;
  int co4 = t % CO4, pi = t / CO4;
  int p = blockIdx.x*PPB + pi;
  int b = p >> 16;
  int rem = p & 65535;
  int y = rem >> 8, xx = rem & 255;
  float4 acc = *(const float4*)(bias + co4*4);
  #pragma unroll
  for (int ci = 0; ci < 3; ++ci)
    for (int dy = 0; dy < 3; ++dy){
      int yy = y + dy - 1;
      if ((unsigned)yy >= 256u) continue;
      for (int dx = 0; dx < 3; ++dx){
        int xg = xx + dx - 1;
        if ((unsigned)xg >= 256u) continue;
        float v = x[(((size_t)b*3 + ci)*256 + yy)*256 + xg];
        int k = ci*9 + dy*3 + dx;
        float4 w = *(const float4*)(wt + (size_t)k*CO + co4*4);
        acc.x += v*w.x; acc.y += v*w.y; acc.z += v*w.z; acc.w += v*w.w;
      }
    }
  float4 o; o.x = silu_f(acc.x); o.y = silu_f(acc.y); o.z = silu_f(acc.z); o.w = silu_f(acc.w);
  *(float4*)(out + (size_t)p*CO + co4*4) = o;
}

// ---------------- MFMA bf16x3 implicit-GEMM conv, CIN=128, NHWC ----------------
// Out tile TR x TC, 4 waves = PXG pixel-groups x COG co-groups.
// A staged per ci-quarter as bf16 hi/lo planes (pad 40 shorts/px).
// B chunks frag-major from global, staged in LDS, register-prefetched.
template<int STRIDE, int TR, int TC, int CO, int WPXF, int WCOR>
__global__ __launch_bounds__(256, 2)
void k_convm(const float* __restrict__ in, const short* __restrict__ bw,
             const float* __restrict__ bias, float* __restrict__ out,
             const float* __restrict__ sc, const float* __restrict__ sh,
             int H_in, int W_in){
  constexpr int IR = TR*STRIDE + 2;
  constexpr int IC = TC*STRIDE + 2;
  constexpr int NCOR = CO/16;
  constexpr int COG = NCOR/WCOR;
  constexpr int PXG = (TR*TC/16)/WPXF;
  static_assert(PXG*COG == 4, "4 waves");
  constexpr int APX = IR*IC;
  constexpr int CHUNK_SHORTS = NCOR*1024;
  constexpr int CF4 = NCOR*128;          // float4 per B chunk
  constexpr int NP = (CF4 + 255)/256;
  __shared__ __align__(16) short Ahi[APX*40];
  __shared__ __align__(16) short Alo[APX*40];
  __shared__ __align__(16) short Bbuf[CHUNK_SHORTS];
  __shared__ float scl[128], shl[128];
  int t = threadIdx.x;
  int w = t >> 6, lane = t & 63;
  int m = lane & 15, kg = lane >> 4;
  int pxg = w / COG, cog = w % COG;
  const int HO = H_in/STRIDE, WO = W_in/STRIDE;
  const int SEGC = WO/TC, NRB = HO/TR;
  int bx = blockIdx.x;
  int segc = bx % SEGC; int rb = (bx/SEGC) % NRB; int b = bx/(SEGC*NRB);
  int oy0 = rb*TR, ox0 = segc*TC;
  int py0 = oy0*STRIDE - 1, px0 = ox0*STRIDE - 1;
  bool hasS = (sc != nullptr);
  if (t < 128){ scl[t] = hasS ? sc[t] : 1.f; shl[t] = hasS ? sh[t] : 0.f; }
  // acc init with bias (per-lane co = rep*16 + m)
  f32x4 acc[WPXF][WCOR];
  #pragma unroll
  for (int r=0;r<WCOR;r++){
    float bvv = bias[(cog*WCOR + r)*16 + m];
    #pragma unroll
    for (int f=0;f<WPXF;f++){
      f32x4 a0 = {bvv, bvv, bvv, bvv};
      acc[f][r] = a0;
    }
  }
  // per-lane A row base (shorts): pixel row = lane&15 of frag
  int abase[WPXF];
  #pragma unroll
  for (int f=0;f<WPXF;f++){
    int fg = pxg*WPXF + f;
    int px = fg*16 + m;
    int orow = px / TC, ocol = px % TC;
    abase[f] = (orow*STRIDE*IC + ocol*STRIDE)*40 + kg*8;
  }
  const float4* bw4 = (const float4*)bw;
  float4 bpre[NP];
  #pragma unroll
  for (int j=0;j<NP;j++){
    int idx = t + j*256;
    if (CF4 >= 256 || idx < CF4) bpre[j] = bw4[idx];
  }
  for (int c=0; c<36; ++c){
    int tap = c % 9, ck = c / 9;
    int dy = tap/3, dx = tap - dy*3;
    __syncthreads();           // prior chunk's LDS reads done
    if (tap == 0){
      // stage A quarter (32 ci) as bf16 hi/lo planes
      for (int e=t; e<APX*8; e+=256){
        int cq = e & 7; int rc = e >> 3;
        int ic = rc % IC, ir = rc / IC;
        int gy = py0 + ir, gx = px0 + ic;
        float4 v = make_float4(0.f,0.f,0.f,0.f);
        if ((unsigned)gy < (unsigned)H_in && (unsigned)gx < (unsigned)W_in){
          int cb = ck*32 + cq*4;
          v = *(const float4*)(in + (((size_t)b*H_in + gy)*(size_t)W_in + gx)*128 + cb);
          v.x = v.x*scl[cb+0] + shl[cb+0];
          v.y = v.y*scl[cb+1] + shl[cb+1];
          v.z = v.z*scl[cb+2] + shl[cb+2];
          v.w = v.w*scl[cb+3] + shl[cb+3];
        }
        float vv[4] = {v.x, v.y, v.z, v.w};
        unsigned hi[4], lo[4];
        #pragma unroll
        for (int k=0;k<4;k++){
          hi[k] = bf16_rne(vv[k]);
          float fh = __uint_as_float(hi[k]<<16);
          lo[k] = bf16_rne(vv[k] - fh);
        }
        uint2 hw, lw;
        hw.x = hi[0] | (hi[1]<<16); hw.y = hi[2] | (hi[3]<<16);
        lw.x = lo[0] | (lo[1]<<16); lw.y = lo[2] | (lo[3]<<16);
        *(uint2*)(&Ahi[rc*40 + cq*4]) = hw;
        *(uint2*)(&Alo[rc*40 + cq*4]) = lw;
      }
    }
    // write B chunk c from prefetch regs
    {
      float4* bb4 = (float4*)Bbuf;
      #pragma unroll
      for (int j=0;j<NP;j++){
        int idx = t + j*256;
        if (CF4 >= 256 || idx < CF4) bb4[idx] = bpre[j];
      }
    }
    __syncthreads();           // staging visible
    // prefetch next B chunk (hidden under MFMA)
    if (c+1 < 36){
      const float4* nb = bw4 + (size_t)(c+1)*CF4;
      #pragma unroll
      for (int j=0;j<NP;j++){
        int idx = t + j*256;
        if (CF4 >= 256 || idx < CF4) bpre[j] = nb[idx];
      }
    }
    // A fragments for this tap
    int toff = (dy*IC + dx)*40;
    short8_t Ah[WPXF], Al[WPXF];
    #pragma unroll
    for (int f=0;f<WPXF;f++){
      Ah[f] = *(const short8_t*)(&Ahi[abase[f] + toff]);
      Al[f] = *(const short8_t*)(&Alo[abase[f] + toff]);
    }
    #pragma unroll
    for (int r=0;r<WCOR;r++){
      int rg = cog*WCOR + r;
      short8_t Bh = *(const short8_t*)(&Bbuf[((rg*2+0)*64 + lane)*8]);
      short8_t Bl = *(const short8_t*)(&Bbuf[((rg*2+1)*64 + lane)*8]);
      #pragma unroll
      for (int f=0;f<WPXF;f++){
        acc[f][r] = __builtin_amdgcn_mfma_f32_16x16x32_bf16(Ah[f], Bh, acc[f][r], 0, 0, 0);
        acc[f][r] = __builtin_amdgcn_mfma_f32_16x16x32_bf16(Al[f], Bh, acc[f][r], 0, 0, 0);
        acc[f][r] = __builtin_amdgcn_mfma_f32_16x16x32_bf16(Ah[f], Bl, acc[f][r], 0, 0, 0);
      }
    }
  }
  // epilogue: D row = (lane>>4)*4 + j (pixel), col = lane&15 (co)
  #pragma unroll
  for (int f=0;f<WPXF;f++){
    int fg = pxg*WPXF + f;
    #pragma unroll
    for (int j=0;j<4;j++){
      int px = fg*16 + kg*4 + j;
      int orow = px / TC, ocol = px % TC;
      float* op = out + (((size_t)b*HO + oy0 + orow)*WO + ox0 + ocol)*CO;
      #pragma unroll
      for (int r=0;r<WCOR;r++){
        int co = (cog*WCOR + r)*16 + m;
        op[co] = silu_f(acc[f][r][j]);
      }
    }
  }
}

// ---------------- CIN=16 3x3 stride2 conv (e0n stem), LDS stride 20 ----------------
template<int CIN, int CO, int STRIDE, int PXB>
__global__ __launch_bounds__(256)
void k_rowconv(const float* __restrict__ in, const float* __restrict__ wt,
               const float* __restrict__ bias, float* __restrict__ out,
               int H_in, int W_in){
  constexpr int WT = PXB*STRIDE + 2;
  constexpr int CO8 = CO/8;
  constexpr int PG = 256/CO8;
  constexpr int PPT = PXB/PG;
  constexpr int SEGS = 128/PXB;
  constexpr int LSTR = CIN + 4;
  __shared__ float lds[WT*LSTR];
  int t = threadIdx.x;
  int co8 = t % CO8, pg = t / CO8;
  int blk = blockIdx.x;
  int seg = blk % SEGS; int oy = (blk/SEGS) & 127; int b = blk/(SEGS*128);
  int x0 = seg*PXB;
  float acc[PPT][8];
  {
    float4 b0 = *(const float4*)(bias + co8*8);
    float4 b1 = *(const float4*)(bias + co8*8 + 4);
    #pragma unroll
    for (int i=0;i<PPT;i++){
      acc[i][0]=b0.x; acc[i][1]=b0.y; acc[i][2]=b0.z; acc[i][3]=b0.w;
      acc[i][4]=b1.x; acc[i][5]=b1.y; acc[i][6]=b1.z; acc[i][7]=b1.w;
    }
  }
  const int gx0 = x0*STRIDE - 1;
  for (int dy=0; dy<3; ++dy){
    int iy = oy*STRIDE + dy - 1;
    if ((unsigned)iy < (unsigned)H_in){
      const float* rowp = in + ((size_t)b*H_in + iy)*(size_t)W_in*CIN;
      for (int i = t; i < WT*(CIN/4); i += 256){
        int col = i / (CIN/4); int cq = i % (CIN/4);
        int gx = gx0 + col;
        float4 v = make_float4(0.f,0.f,0.f,0.f);
        if ((unsigned)gx < (unsigned)W_in)
          v = *(const float4*)(rowp + (size_t)gx*CIN + cq*4);
        *(float4*)(&lds[col*LSTR + cq*4]) = v;
      }
      __syncthreads();
      for (int dx=0; dx<3; ++dx){
        for (int cq=0; cq<CIN/4; ++cq){
          float4 a4[PPT];
          #pragma unroll
          for (int i=0;i<PPT;i++){
            int lx = (pg*PPT + i)*STRIDE + dx;
            a4[i] = *(const float4*)(&lds[lx*LSTR + cq*4]);
          }
          const float* wk = wt + ((size_t)(cq*4)*9 + dy*3 + dx)*CO + co8*8;
          #pragma unroll
          for (int cc=0; cc<4; ++cc){
            float4 w0 = *(const float4*)(wk + (size_t)cc*9*CO);
            float4 w1 = *(const float4*)(wk + (size_t)cc*9*CO + 4);
            #pragma unroll
            for (int i=0;i<PPT;i++){
              float av = (cc==0) ? a4[i].x : (cc==1) ? a4[i].y : (cc==2) ? a4[i].z : a4[i].w;
              acc[i][0] += av*w0.x; acc[i][1] += av*w0.y; acc[i][2] += av*w0.z; acc[i][3] += av*w0.w;
              acc[i][4] += av*w1.x; acc[i][5] += av*w1.y; acc[i][6] += av*w1.z; acc[i][7] += av*w1.w;
            }
          }
        }
      }
      __syncthreads();
    }
  }
  #pragma unroll
  for (int i=0;i<PPT;i++){
    int px = x0 + pg*PPT + i;
    float4 o0, o1;
    o0.x = silu_f(acc[i][0]); o0.y = silu_f(acc[i][1]); o0.z = silu_f(acc[i][2]); o0.w = silu_f(acc[i][3]);
    o1.x = silu_f(acc[i][4]); o1.y = silu_f(acc[i][5]); o1.z = silu_f(acc[i][6]); o1.w = silu_f(acc[i][7]);
    float* op = out + (((size_t)b*128 + oy)*128 + px)*CO + co8*8;
    *(float4*)op = o0; *(float4*)(op+4) = o1;
  }
}

// ---------------- memcell weights ----------------
__global__ __launch_bounds__(256)
void k_weights(const float* __restrict__ z, const float* __restrict__ zhat,
               float* __restrict__ wT, const float* __restrict__ sc,
               const float* __restrict__ sh, int T){
  __shared__ float zl[128*16];
  __shared__ float zn[128];
  __shared__ float scl[16], shl[16];
  int t = threadIdx.x;
  if (t < 128){
    float s2 = 0.f;
    #pragma unroll
    for (int j=0;j<16;j++){ float v = zhat[t*16+j]; zl[t*16+j] = v; s2 += v*v; }
    zn[t] = s2;
  }
  if (t < 16){ scl[t] = sc ? sc[t] : 1.f; shl[t] = sh ? sh[t] : 0.f; }
  __syncthreads();
  size_t tok = (size_t)blockIdx.x*256 + t;
  float zr[16];
  #pragma unroll
  for (int q=0;q<4;q++){
    float4 v = *(const float4*)(z + tok*16 + q*4);
    zr[q*4+0] = v.x*scl[q*4+0]+shl[q*4+0];
    zr[q*4+1] = v.y*scl[q*4+1]+shl[q*4+1];
    zr[q*4+2] = v.z*scl[q*4+2]+shl[q*4+2];
    zr[q*4+3] = v.w*scl[q*4+3]+shl[q*4+3];
  }
  float mx = -1e30f;
  for (int m=0;m<128;m++){
    float d=0.f;
    #pragma unroll
    for (int j=0;j<16;j++) d += zr[j]*zl[m*16+j];
    float s = 5.0f*(2.f*d - zn[m]);
    mx = fmaxf(mx, s);
  }
  float sum=0.f;
  for (int m=0;m<128;m++){
    float d=0.f;
    #pragma unroll
    for (int j=0;j<16;j++) d += zr[j]*zl[m*16+j];
    sum += __expf(5.0f*(2.f*d - zn[m]) - mx);
  }
  float inv = 1.f/sum;
  for (int m=0;m<128;m++){
    float d=0.f;
    #pragma unroll
    for (int j=0;j<16;j++) d += zr[j]*zl[m*16+j];
    wT[(size_t)m*T + tok] = __expf(5.0f*(2.f*d - zn[m]) - mx)*inv;
  }
}

// ---------------- S=128 GEMM ----------------
template<bool ADD, bool DOTANH, bool STATS, bool MAT2>
__global__ __launch_bounds__(256)
void k_gemm128(const float* __restrict__ wT, const float* __restrict__ mat1,
               const float* __restrict__ mat2, const float* __restrict__ addsrc,
               float* __restrict__ dst, double* __restrict__ stats, int T){
  __shared__ float4 ml4[128*32];
  __shared__ float ssum[128], ssq[128];
  int t = threadIdx.x;
  if (STATS && t < 128){ ssum[t]=0.f; ssq[t]=0.f; }
  for (int i=t; i < 128*32; i += 256){
    float4 v = ((const float4*)mat1)[i];
    if (MAT2){ float4 u = ((const float4*)mat2)[i]; v.x+=u.x; v.y+=u.y; v.z+=u.z; v.w+=u.w; }
    ml4[i] = v;
  }
  __syncthreads();
  int s16 = t & 15, tg = t >> 4;
  size_t tb = (size_t)blockIdx.x*64;
  float accA[4][4], accB[4][4];
  #pragma unroll
  for (int i=0;i<4;i++) for (int j=0;j<4;j++){ accA[i][j]=0.f; accB[i][j]=0.f; }
  const float* wp = wT + tb + tg*4;
  #pragma unroll 4
  for (int m=0;m<128;m++){
    float4 wv = *(const float4*)(wp + (size_t)m*T);
    float4 c0 = ml4[m*32 + s16];
    float4 c1 = ml4[m*32 + 16 + s16];
    float w[4] = {wv.x,wv.y,wv.z,wv.w};
    #pragma unroll
    for (int i=0;i<4;i++){
      accA[i][0] += w[i]*c0.x; accA[i][1] += w[i]*c0.y; accA[i][2] += w[i]*c0.z; accA[i][3] += w[i]*c0.w;
      accB[i][0] += w[i]*c1.x; accB[i][1] += w[i]*c1.y; accB[i][2] += w[i]*c1.z; accB[i][3] += w[i]*c1.w;
    }
  }
  int colA = s16*4, colB = 64 + s16*4;
  float lsA[4], lqA[4], lsB[4], lqB[4];
  #pragma unroll
  for (int j=0;j<4;j++){ lsA[j]=0.f; lqA[j]=0.f; lsB[j]=0.f; lqB[j]=0.f; }
  #pragma unroll
  for (int i=0;i<4;i++){
    size_t tok = tb + tg*4 + i;
    float oA[4], oB[4];
    #pragma unroll
    for (int j=0;j<4;j++){ oA[j]=accA[i][j]; oB[j]=accB[i][j]; }
    if (ADD){
      float4 a0 = *(const float4*)(addsrc + tok*128 + colA);
      float4 a1 = *(const float4*)(addsrc + tok*128 + colB);
      oA[0]+=a0.x; oA[1]+=a0.y; oA[2]+=a0.z; oA[3]+=a0.w;
      oB[0]+=a1.x; oB[1]+=a1.y; oB[2]+=a1.z; oB[3]+=a1.w;
    }
    if (DOTANH){
      #pragma unroll
      for (int j=0;j<4;j++){ oA[j]=tanhf(oA[j]); oB[j]=tanhf(oB[j]); }
    }
    float4 r0 = {oA[0],oA[1],oA[2],oA[3]}, r1 = {oB[0],oB[1],oB[2],oB[3]};
    *(float4*)(dst + tok*128 + colA) = r0;
    *(float4*)(dst + tok*128 + colB) = r1;
    if (STATS){
      #pragma unroll
      for (int j=0;j<4;j++){
        lsA[j]+=oA[j]; lqA[j]+=oA[j]*oA[j];
        lsB[j]+=oB[j]; lqB[j]+=oB[j]*oB[j];
      }
    }
  }
  if (STATS){
    #pragma unroll
    for (int j=0;j<4;j++){
      atomicAdd(&ssum[colA+j], lsA[j]); atomicAdd(&ssq[colA+j], lqA[j]);
      atomicAdd(&ssum[colB+j], lsB[j]); atomicAdd(&ssq[colB+j], lqB[j]);
    }
    __syncthreads();
    if (t < 128){
      atomicAdd(&stats[t], (double)ssum[t]);
      atomicAdd(&stats[128+t], (double)ssq[t]);
    }
  }
}

// ---------------- S=16 GEMM ----------------
template<bool ADD, bool DOTANH, bool STATS>
__global__ __launch_bounds__(256)
void k_gemm16(const float* __restrict__ wT, const float* __restrict__ mat1,
              const float* __restrict__ addsrc, float* __restrict__ dst,
              double* __restrict__ stats, int T){
  __shared__ float ml[128*16];
  __shared__ float ssum[16], ssq[16];
  int t = threadIdx.x;
  if (STATS && t < 16){ ssum[t]=0.f; ssq[t]=0.f; }
  for (int i=t; i < 128*4; i += 256)
    ((float4*)ml)[i] = ((const float4*)mat1)[i];
  __syncthreads();
  size_t tb = (size_t)blockIdx.x*128;
  int s8 = t & 1, tg = t >> 1;
  float acc[8];
  #pragma unroll
  for (int j=0;j<8;j++) acc[j]=0.f;
  size_t tok = tb + tg;
  const float* wp = wT + tok;
  #pragma unroll 4
  for (int m=0;m<128;m++){
    float wv = wp[(size_t)m*T];
    float4 c0 = *(const float4*)(&ml[m*16 + s8*8]);
    float4 c1 = *(const float4*)(&ml[m*16 + s8*8 + 4]);
    acc[0]+=wv*c0.x; acc[1]+=wv*c0.y; acc[2]+=wv*c0.z; acc[3]+=wv*c0.w;
    acc[4]+=wv*c1.x; acc[5]+=wv*c1.y; acc[6]+=wv*c1.z; acc[7]+=wv*c1.w;
  }
  float o[8];
  #pragma unroll
  for (int j=0;j<8;j++) o[j]=acc[j];
  if (ADD){
    float4 a0 = *(const float4*)(addsrc + tok*16 + s8*8);
    float4 a1 = *(const float4*)(addsrc + tok*16 + s8*8+4);
    o[0]+=a0.x; o[1]+=a0.y; o[2]+=a0.z; o[3]+=a0.w;
    o[4]+=a1.x; o[5]+=a1.y; o[6]+=a1.z; o[7]+=a1.w;
  }
  if (DOTANH){
    #pragma unroll
    for (int j=0;j<8;j++) o[j]=tanhf(o[j]);
  }
  float4 r0 = {o[0],o[1],o[2],o[3]}, r1 = {o[4],o[5],o[6],o[7]};
  *(float4*)(dst + tok*16 + s8*8) = r0;
  *(float4*)(dst + tok*16 + s8*8 + 4) = r1;
  if (STATS){
    #pragma unroll
    for (int j=0;j<8;j++){ atomicAdd(&ssum[s8*8+j], o[j]); atomicAdd(&ssq[s8*8+j], o[j]*o[j]); }
    __syncthreads();
    if (t < 16){
      atomicAdd(&stats[t], (double)ssum[t]);
      atomicAdd(&stats[16+t], (double)ssq[t]);
    }
  }
}

// ---------------- delta[m][s] += sum_t wT[m][t] * ALPHA*(Tstar - read)[t][s] ----------------
template<int S>
__global__ __launch_bounds__(256)
void k_delta(const float* __restrict__ wT, const float* __restrict__ tstar,
             const float* __restrict__ rd, float* __restrict__ delta, int T, int KCH){
  constexpr int SUB = 64;
  constexpr int SJ = (S==128)?8:1;
  __shared__ float wl[128*66];
  __shared__ float dl[SUB*S];
  int t = threadIdx.x;
  int tm = t >> 4, ts = t & 15;
  size_t base = (size_t)blockIdx.x * KCH;
  float acc[8][SJ];
  #pragma unroll
  for (int i=0;i<8;i++) for (int j=0;j<SJ;j++) acc[i][j]=0.f;
  for (int c0=0; c0<KCH; c0+=SUB){
    for (int i=t; i<128*16; i+=256){
      int m = i >> 4; int tq = i & 15;
      float4 v = *(const float4*)(wT + (size_t)m*T + base + c0 + tq*4);
      float* wp = &wl[m*66 + tq*4];
      *(float2*)(wp)   = make_float2(v.x, v.y);
      *(float2*)(wp+2) = make_float2(v.z, v.w);
    }
    for (int i=t; i<SUB*S/4; i+=256){
      int tt = i/(S/4); int sq = i%(S/4);
      size_t tok = base + c0 + tt;
      float4 a = *(const float4*)(tstar + tok*S + sq*4);
      float4 r = *(const float4*)(rd + tok*S + sq*4);
      float4 d; d.x = 0.1f*(a.x-r.x); d.y = 0.1f*(a.y-r.y); d.z = 0.1f*(a.z-r.z); d.w = 0.1f*(a.w-r.w);
      *(float4*)(&dl[tt*S + sq*4]) = d;
    }
    __syncthreads();
    for (int tt=0; tt<SUB; ++tt){
      float wv[8];
      #pragma unroll
      for (int i=0;i<8;i++) wv[i] = wl[(tm+16*i)*66 + tt];
      if constexpr (S==128){
        float4 d0 = *(const float4*)(&dl[tt*128 + ts*4]);
        float4 d1 = *(const float4*)(&dl[tt*128 + 64 + ts*4]);
        #pragma unroll
        for (int i=0;i<8;i++){
          acc[i][0] += wv[i]*d0.x; acc[i][1] += wv[i]*d0.y;
          acc[i][2] += wv[i]*d0.z; acc[i][3] += wv[i]*d0.w;
          acc[i][4] += wv[i]*d1.x; acc[i][5] += wv[i]*d1.y;
          acc[i][6] += wv[i]*d1.z; acc[i][7] += wv[i]*d1.w;
        }
      } else {
        float dv = dl[tt*16 + ts];
        #pragma unroll
        for (int i=0;i<8;i++) acc[i][0] += wv[i]*dv;
      }
    }
    __syncthreads();
  }
  if constexpr (S==128){
    #pragma unroll
    for (int i=0;i<8;i++){
      #pragma unroll
      for (int j=0;j<4;j++){
        atomicAdd(&delta[(tm+16*i)*128 + ts*4 + j], acc[i][j]);
        atomicAdd(&delta[(tm+16*i)*128 + 64 + ts*4 + j], acc[i][4+j]);
      }
    }
  } else {
    #pragma unroll
    for (int i=0;i<8;i++)
      atomicAdd(&delta[(tm+16*i)*16 + ts], acc[i][0]);
  }
}

// ---------------- BN finalize ----------------
__global__ void k_bnfin(const double* __restrict__ stats, const float* __restrict__ g,
                        const float* __restrict__ b, float* __restrict__ sc,
                        float* __restrict__ sh, int C, double invT){
  int c = threadIdx.x; if (c >= C) return;
  double mean = stats[c]*invT;
  double var = stats[C+c]*invT - mean*mean;
  if (var < 0.0) var = 0.0;
  double s = (double)g[c] / sqrt(var + 1e-5);
  sc[c] = (float)s; sh[c] = (float)((double)b[c] - mean*s);
}

// ---------------- deconv 4x4 stride2 pad1: global-input, weights in LDS ----------------
__global__ __launch_bounds__(256)
void k_deconv(const float* __restrict__ in, const float* __restrict__ wd,
              const float* __restrict__ bias, float* __restrict__ out,
              const float* __restrict__ sc, const float* __restrict__ sh){
  __shared__ float wl[16*384];
  __shared__ float scl[128], shl[128];
  int t = threadIdx.x;
  int oy = blockIdx.x & 255; int b = blockIdx.x >> 8;
  if (t < 128){ scl[t]=sc[t]; shl[t]=sh[t]; }
  for (int i=t; i<1536; i+=256)
    ((float4*)wl)[i] = ((const float4*)wd)[i];
  __syncthreads();
  int ox = t;
  int p = (oy+1)&1;
  int iy_hi = (oy+1-p)>>1;
  int px_ = (ox+1)&1;
  int ix_hi = (ox+1-px_)>>1;
  float acc0=bias[0], acc1=bias[1], acc2=bias[2];
  #pragma unroll
  for (int ry=0; ry<2; ++ry){
    int iy = iy_hi - 1 + ry;
    if ((unsigned)iy >= 128u) continue;
    int ky = p + 2*(1-ry);
    #pragma unroll
    for (int cx=0; cx<2; ++cx){
      int ix = ix_hi - (1-cx);
      if ((unsigned)ix >= 128u) continue;
      int kx = px_ + 2*(1-cx);
      int tap = ky*4 + kx;
      const float* ip = in + (((size_t)b*128 + iy)*128 + ix)*128;
      const float* wp = &wl[tap*384];
      for (int cq=0; cq<32; ++cq){
        float4 a = *(const float4*)(ip + cq*4);
        a.x = a.x*scl[cq*4+0]+shl[cq*4+0];
        a.y = a.y*scl[cq*4+1]+shl[cq*4+1];
        a.z = a.z*scl[cq*4+2]+shl[cq*4+2];
        a.w = a.w*scl[cq*4+3]+shl[cq*4+3];
        float4 w0 = *(const float4*)(wp + cq*12);
        float4 w1 = *(const float4*)(wp + cq*12+4);
        float4 w2 = *(const float4*)(wp + cq*12+8);
        acc0 += a.x*w0.x + a.y*w0.w + a.z*w1.z + a.w*w2.y;
        acc1 += a.x*w0.y + a.y*w1.x + a.z*w1.w + a.w*w2.z;
        acc2 += a.x*w0.z + a.y*w1.y + a.z*w2.x + a.w*w2.w;
      }
    }
  }
  float* op = out + (((size_t)b*256 + oy)*256 + ox)*3;
  op[0]=silu_f(acc0); op[1]=silu_f(acc1); op[2]=silu_f(acc2);
}

// ---------------- final conv 3x3, 3->3, NHWC in -> NCHW out, silu ----------------
__global__ __launch_bounds__(256)
void k_conv33(const float* __restrict__ in, const float* __restrict__ wt,
              const float* __restrict__ bias, float* __restrict__ out){
  int pidx = blockIdx.x*256 + threadIdx.x;
  int b = pidx >> 16; int rem = pidx & 65535;
  int y = rem >> 8, x = rem & 255;
  float a0=bias[0], a1=bias[1], a2=bias[2];
  for (int dy=0;dy<3;dy++){
    int yy=y+dy-1; if((unsigned)yy>=256u) continue;
    for (int dx=0;dx<3;dx++){
      int xx2=x+dx-1; if((unsigned)xx2>=256u) continue;
      const float* ip = in + (((size_t)b*256+yy)*256+xx2)*3;
      #pragma unroll
      for (int ci=0;ci<3;ci++){
        float v = ip[ci];
        const float* wp = wt + (ci*9 + dy*3 + dx)*3;
        a0 += v*wp[0]; a1 += v*wp[1]; a2 += v*wp[2];
      }
    }
  }
  size_t o = (size_t)b*3*65536 + (size_t)y*256 + x;
  out[o]         = silu_f(a0);
  out[o+65536]   = silu_f(a1);
  out[o+2*65536] = silu_f(a2);
}

// ================= host side =================
extern "C" void kernel_launch(void* const* d_in, const int* in_sizes, int n_in,
                              void* d_out, int out_size, void* d_ws, size_t ws_size,
                              hipStream_t stream) {
  const float* x       = (const float*)d_in[0];
  const float* e0n_w1  = (const float*)d_in[1];
  const float* e0n_b1  = (const float*)d_in[2];
  const float* e0n_w2  = (const float*)d_in[3];
  const float* e0n_b2  = (const float*)d_in[4];
  const float* e0s_w1  = (const float*)d_in[5];
  const float* e0s_b1  = (const float*)d_in[6];
  const float* e0s_w2  = (const float*)d_in[7];
  const float* e0s_b2  = (const float*)d_in[8];
  const float* bnn_w1  = (const float*)d_in[9];
  const float* bnn_b1  = (const float*)d_in[10];
  const float* bnn_w2  = (const float*)d_in[11];
  const float* bnn_b2  = (const float*)d_in[12];
  const float* bns_w1  = (const float*)d_in[13];
  const float* bns_b1  = (const float*)d_in[14];
  const float* bns_w2  = (const float*)d_in[15];
  const float* bns_b2  = (const float*)d_in[16];
  const float* d0_wt   = (const float*)d_in[17];
  const float* d0_bt   = (const float*)d_in[18];
  const float* d0_wc   = (const float*)d_in[19];
  const float* d0_bc   = (const float*)d_in[20];
  const float* g0      = (const float*)d_in[21];
  const float* be0     = (const float*)d_in[22];
  const float* gb      = (const float*)d_in[23];
  const float* bb      = (const float*)d_in[24];
  const float* gd      = (const float*)d_in[25];
  const float* bd      = (const float*)d_in[26];
  const float* c0_zhat = (const float*)d_in[27];
  const float* c0_That = (const float*)d_in[28];
  const float* cb_zhat = (const float*)d_in[29];
  const float* cb_That = (const float*)d_in[30];

  char* wsb = (char*)d_ws;
  const size_t SLOT = 33554432ull;
  const size_t R1 = 4*SLOT;
  const size_t R2 = R1 + 16777216ull;
  const size_t R3 = R2 + 4194304ull;
  const size_t R4 = R3 + 33554432ull;
  const size_t WB = R4 + 81920ull;
  const size_t WC = WB + 50176ull;
  const size_t NEED = WC + 1916928ull;
  if (ws_size < NEED) return;

  float* t1    = (float*)(wsb + 0);
  float* w0T   = (float*)(wsb + 0);
  float* u2    = (float*)(wsb + 0);
  float* xt3   = (float*)(wsb + 0);
  float* read0 = (float*)(wsb + SLOT);
  float* w2T   = (float*)(wsb + SLOT);
  float* xt1   = (float*)(wsb + 2*SLOT);
  float* wbT   = (float*)(wsb + 2*SLOT);
  float* u1    = (float*)(wsb + 3*SLOT);
  float* t0    = (float*)(wsb + R1);
  float* bnnb  = (float*)(wsb + R1);
  float* bnsb  = (float*)(wsb + R1 + 4194304ull);
  float* readb = (float*)(wsb + R1 + 8388608ull);
  float* xt2   = (float*)(wsb + R1 + 12582912ull);
  float* e0n   = (float*)(wsb + R2);
  float* y1    = (float*)(wsb + R2);
  float* e0s   = (float*)(wsb + R3);
  float* delta0 = (float*)(wsb + R4);
  float* deltab = (float*)(wsb + R4 + 65536ull);
  double* stats0 = (double*)(wsb + R4 + 73728ull);
  double* statsb = (double*)(wsb + R4 + 75776ull);
  double* statsd = (double*)(wsb + R4 + 76288ull);
  float* sc0 = (float*)(wsb + R4 + 78336ull);
  float* sh0 = (float*)(wsb + R4 + 78848ull);
  float* scb = (float*)(wsb + R4 + 79360ull);
  float* shb = (float*)(wsb + R4 + 79872ull);
  float* scd = (float*)(wsb + R4 + 80384ull);
  float* shd = (float*)(wsb + R4 + 80896ull);
  float* wt_e0n1 = (float*)(wsb + WB);
  float* wt_e0n2 = (float*)(wsb + WB + 2048ull);
  float* wt_e0s1 = (float*)(wsb + WB + 11264ull);
  float* wt_d0c  = (float*)(wsb + WB + 25088ull);
  float* wd_dec  = (float*)(wsb + WB + 25600ull);
  short* wq_e0s2 = (short*)(wsb + WC);
  short* wq_bnn1 = (short*)(wsb + WC + 589824ull);
  short* wq_bns1 = (short*)(wsb + WC + 1179648ull);
  short* wq_bnn2 = (short*)(wsb + WC + 1769472ull);
  short* wq_bns2 = (short*)(wsb + WC + 1843200ull);

  const int T = 65536;
  const double invT = 1.0/65536.0;

  k_zero<<<77, 256, 0, stream>>>((float*)(wsb + R4), 19584);

  XArgs xa;
  xa.j[0] = { e0n_w1, wt_e0n1, 3, 16, 432, 0 };
  xa.j[1] = { e0n_w2, wt_e0n2, 16, 16, 2304, 0 };
  xa.j[2] = { e0s_w1, wt_e0s1, 3, 128, 3456, 0 };
  xa.j[3] = { d0_wc,  wt_d0c,  3, 3, 81, 0 };
  xa.j[4] = { d0_wt,  wd_dec,  128, 3, 6144, 2 };
  k_xform<<<dim3(24,5), 256, 0, stream>>>(xa);

  WArgs wa;
  wa.j[0] = { e0s_w2, wq_e0s2, 8, 294912 };
  wa.j[1] = { bnn_w1, wq_bnn1, 8, 294912 };
  wa.j[2] = { bns_w1, wq_bns1, 8, 294912 };
  wa.j[3] = { bnn_w2, wq_bnn2, 1, 36864 };
  wa.j[4] = { bns_w2, wq_bns2, 1, 36864 };
  k_wsplit<<<dim3(1152,5), 256, 0, stream>>>(wa);

  // encoder stems
  k_conv_cin3<16><<<4096, 256, 0, stream>>>(x, wt_e0n1, e0n_b1, t0);
  k_conv_cin3<128><<<32768, 256, 0, stream>>>(x, wt_e0s1, e0s_b1, t1);
  k_rowconv<16,16,2,128><<<512, 256, 0, stream>>>(t0, wt_e0n2, e0n_b2, e0n, 256, 256);
  // e0s conv2 (stride2): out-tile 8x8, 1024 blocks
  k_convm<2,8,8,128,2,4><<<1024, 256, 0, stream>>>(t1, wq_e0s2, e0s_b2, e0s, nullptr, nullptr, 256, 256);

  // memcell 0 write
  k_weights<<<256, 256, 0, stream>>>(e0n, c0_zhat, w0T, nullptr, nullptr, T);
  k_gemm128<false,false,false,false><<<1024, 256, 0, stream>>>(w0T, c0_That, nullptr, nullptr, read0, nullptr, T);
  k_delta<128><<<512, 256, 0, stream>>>(w0T, e0s, read0, delta0, T, 128);
  k_gemm128<true,true,true,false><<<1024, 256, 0, stream>>>(w0T, delta0, nullptr, read0, xt1, stats0, T);
  k_bnfin<<<1, 128, 0, stream>>>(stats0, g0, be0, sc0, sh0, 128, invT);

  // bottleneck branches (bn folded into A staging)
  k_convm<1,16,8,128,4,4><<<512, 256, 0, stream>>>(xt1, wq_bnn1, bnn_b1, u1, sc0, sh0, 128, 128);
  k_convm<1,8,16,16,2,1><<<512, 256, 0, stream>>>(u1, wq_bnn2, bnn_b2, bnnb, nullptr, nullptr, 128, 128);
  k_convm<1,16,8,128,4,4><<<512, 256, 0, stream>>>(xt1, wq_bns1, bns_b1, u2, sc0, sh0, 128, 128);
  k_convm<1,8,16,16,2,1><<<512, 256, 0, stream>>>(u2, wq_bns2, bns_b2, bnsb, nullptr, nullptr, 128, 128);

  // memcell b write
  k_weights<<<256, 256, 0, stream>>>(bnnb, cb_zhat, wbT, nullptr, nullptr, T);
  k_gemm16<false,false,false><<<512, 256, 0, stream>>>(wbT, cb_That, nullptr, readb, nullptr, T);
  k_delta<16><<<512, 256, 0, stream>>>(wbT, bnsb, readb, deltab, T, 128);
  k_gemm16<true,true,true><<<512, 256, 0, stream>>>(wbT, deltab, readb, xt2, statsb, T);
  k_bnfin<<<1, 64, 0, stream>>>(statsb, gb, bb, scb, shb, 16, invT);

  // decoder recall-read against cell 0
  k_weights<<<256, 256, 0, stream>>>(xt2, c0_zhat, w2T, scb, shb, T);
  k_gemm128<false,true,true,true><<<1024, 256, 0, stream>>>(w2T, c0_That, delta0, nullptr, xt3, statsd, T);
  k_bnfin<<<1, 128, 0, stream>>>(statsd, gd, bd, scd, shd, 128, invT);

  // deconv + final conv
  k_deconv<<<1024, 256, 0, stream>>>(xt3, wd_dec, d0_bt, y1, scd, shd);
  k_conv33<<<1024, 256, 0, stream>>>(y1, wt_d0c, d0_bc, (float*)d_out);
}